// Round 1
// baseline (4940.962 us; speedup 1.0000x reference)
//
#include <hip/hip_runtime.h>

#define NNODES 50000
#define NEDGES 400000
#define TE 16      // edges (or nodes) per block
#define AP 18      // A_T column pad (TE=16 -> 18, keeps float2 8B-aligned)
#define VP 50      // V_T column pad (3*TE=48 -> 50)
#define WP 132     // W tile column pad (128 -> 132, keeps float4 16B-aligned, staggers banks)

constexpr float RSQRT3 = 0.57735026918962576f;
constexpr float INV_M1 = 0.062257280630559f;   // 1/sqrt(130+128)
constexpr float INV_M2 = 0.088388347648318f;   // 1/sqrt(64+64)
constexpr float INV_U0 = 0.0625f;              // 1/sqrt(128+128)
constexpr float INV_U1 = 0.088388347648318f;   // 1/sqrt(64+64)

__device__ __forceinline__ float fast_sigmoid(float x){ return 1.0f / (1.0f + __expf(-x)); }

// ---- W tile loader: rows k0..k0+15 of a [K][TO] row-major weight into LDS ----
template<int TO>
__device__ __forceinline__ void load_W16(float (*W_s)[WP], const float* __restrict__ W,
                                         int k0, int K, int t){
  constexpr int SH = (TO == 128) ? 7 : 6;
  #pragma unroll
  for (int idx = t; idx < 16*TO; idx += 256){
    int r = idx >> SH, c = idx & (TO-1);
    if (k0 + r < K) W_s[r][c] = W[((k0 + r) << SH) + c];
  }
}

// ---- GEMM, 128-wide output: thread (og=t&31 -> 4 cols, eg=t>>5 -> 2 rows/edges) ----
template<int K, int ROWBASE>
__device__ __forceinline__ void gemm_s(float acc[4][2], const float* __restrict__ W,
                                       float (*A_T)[AP], float (*W_s)[WP], int t){
  const int og = t & 31;
  const int eg = t >> 5;
  for (int k0 = 0; k0 < K; k0 += 16){
    __syncthreads();
    load_W16<128>(W_s, W, k0, K, t);
    __syncthreads();
    const int kend = (K - k0 < 16) ? (K - k0) : 16;
    #pragma unroll 4
    for (int kk = 0; kk < kend; kk++){
      const float4 w = *(const float4*)(&W_s[kk][og*4]);
      const float2 a = *(const float2*)(&A_T[ROWBASE + k0 + kk][eg*2]);
      acc[0][0] = fmaf(w.x, a.x, acc[0][0]); acc[0][1] = fmaf(w.x, a.y, acc[0][1]);
      acc[1][0] = fmaf(w.y, a.x, acc[1][0]); acc[1][1] = fmaf(w.y, a.y, acc[1][1]);
      acc[2][0] = fmaf(w.z, a.x, acc[2][0]); acc[2][1] = fmaf(w.z, a.y, acc[2][1]);
      acc[3][0] = fmaf(w.w, a.x, acc[3][0]); acc[3][1] = fmaf(w.w, a.y, acc[3][1]);
    }
  }
}

// ---- GEMM, 64-wide output: thread (og=t&15 -> 4 cols, eg=t>>4 -> 1 row/edge) ----
template<int K, int ROWBASE>
__device__ __forceinline__ void gemm_t(float acc[4], const float* __restrict__ W,
                                       float (*A_T)[AP], float (*W_s)[WP], int t){
  const int og = t & 15;
  const int eg = t >> 4;
  for (int k0 = 0; k0 < K; k0 += 16){
    __syncthreads();
    load_W16<64>(W_s, W, k0, K, t);
    __syncthreads();
    const int kend = (K - k0 < 16) ? (K - k0) : 16;
    #pragma unroll 4
    for (int kk = 0; kk < kend; kk++){
      const float4 w = *(const float4*)(&W_s[kk][og*4]);
      const float a = A_T[ROWBASE + k0 + kk][eg];
      acc[0] = fmaf(w.x, a, acc[0]); acc[1] = fmaf(w.y, a, acc[1]);
      acc[2] = fmaf(w.z, a, acc[2]); acc[3] = fmaf(w.w, a, acc[3]);
    }
  }
}

// ---- vector-channel GEMM: 3 i-components share the W tile ----
template<int K>
__device__ __forceinline__ void gemm_u(float acc[3][4], const float* __restrict__ W,
                                       float (*V_T)[VP], float (*W_s)[WP], int t){
  const int og = t & 15;
  const int eg = t >> 4;
  for (int k0 = 0; k0 < K; k0 += 16){
    __syncthreads();
    load_W16<64>(W_s, W, k0, K, t);
    __syncthreads();
    #pragma unroll 4
    for (int kk = 0; kk < 16; kk++){
      const int k = k0 + kk;
      const float4 w = *(const float4*)(&W_s[kk][og*4]);
      const float a0 = V_T[k][eg], a1 = V_T[k][16+eg], a2 = V_T[k][32+eg];
      acc[0][0] = fmaf(w.x,a0,acc[0][0]); acc[0][1] = fmaf(w.y,a0,acc[0][1]);
      acc[0][2] = fmaf(w.z,a0,acc[0][2]); acc[0][3] = fmaf(w.w,a0,acc[0][3]);
      acc[1][0] = fmaf(w.x,a1,acc[1][0]); acc[1][1] = fmaf(w.y,a1,acc[1][1]);
      acc[1][2] = fmaf(w.z,a1,acc[1][2]); acc[1][3] = fmaf(w.w,a1,acc[1][3]);
      acc[2][0] = fmaf(w.x,a2,acc[2][0]); acc[2][1] = fmaf(w.y,a2,acc[2][1]);
      acc[2][2] = fmaf(w.z,a2,acc[2][2]); acc[2][3] = fmaf(w.w,a2,acc[2][3]);
    }
  }
}

// =================== edge kernel: m1 (gated) -> m2 (gated) -> atomic aggregate ===================
__global__ __launch_bounds__(256, 2) void edge_kernel(
    const float* __restrict__ node_s, const float* __restrict__ node_v,
    const float* __restrict__ edge_attr_s, const float* __restrict__ edge_attr_v,
    const float* __restrict__ add_feat,
    const int* __restrict__ senders, const int* __restrict__ receivers,
    const float* __restrict__ Wss1, const float* __restrict__ Wvs1,
    const float* __restrict__ Wsv1, const float* __restrict__ Wvv1,
    const float* __restrict__ b1,
    const float* __restrict__ Wss2, const float* __restrict__ Wvs2,
    const float* __restrict__ Wsv2, const float* __restrict__ Wvv2,
    const float* __restrict__ b2,
    float* __restrict__ out)
{
  __shared__ float A_T[258][AP];   // m1: rows 0..129 = xs, 130..257 = Q/sqrt3; m2 reuses rows 0..127
  __shared__ float V_T[128][VP];   // raw xv (col = i*16+e); rows 0..63 reused for gated mv
  __shared__ float W_s[16][WP];
  __shared__ float s_buf[TE][129];
  __shared__ float a_s_sh[TE];
  __shared__ float av_sh[TE][3];
  __shared__ int snd_sh[TE];
  __shared__ int rcv_sh[TE];

  const int t = threadIdx.x;
  const int e0 = blockIdx.x * TE;

  if (t < TE){
    a_s_sh[t] = edge_attr_s[e0 + t];
    snd_sh[t] = senders[e0 + t];
    rcv_sh[t] = receivers[e0 + t];
  }
  if (t < TE*3){
    av_sh[t/3][t%3] = edge_attr_v[e0*3 + t];
  }
  __syncthreads();

  { // stage xs / xv for 16 edges (16 threads per edge, float4 gathers)
    const int e = t >> 4, l = t & 15;
    const int snd = snd_sh[e], rcv = rcv_sh[e];
    float4 v4 = ((const float4*)(node_s + (size_t)snd*64))[l];
    A_T[l*4+0][e] = v4.x; A_T[l*4+1][e] = v4.y;
    A_T[l*4+2][e] = v4.z; A_T[l*4+3][e] = v4.w;
    v4 = ((const float4*)(node_s + (size_t)rcv*64))[l];
    A_T[64+l*4+0][e] = v4.x; A_T[64+l*4+1][e] = v4.y;
    A_T[64+l*4+2][e] = v4.z; A_T[64+l*4+3][e] = v4.w;
    if (l == 0){
      A_T[128][e] = add_feat[(e0+e)*2 + 0];
      A_T[129][e] = add_feat[(e0+e)*2 + 1];
    }
    const float4* pvs = (const float4*)(node_v + (size_t)snd*192);
    const float4* pvr = (const float4*)(node_v + (size_t)rcv*192);
    #pragma unroll
    for (int q = 0; q < 3; q++){
      float4 w4 = pvs[l*3+q];
      int f = (l*3+q)*4;
      float vals[4] = {w4.x, w4.y, w4.z, w4.w};
      #pragma unroll
      for (int j = 0; j < 4; j++){
        int ff = f + j, vv = ff/3, ii = ff - vv*3;
        V_T[vv][ii*16 + e] = vals[j];
      }
      w4 = pvr[l*3+q];
      float vals2[4] = {w4.x, w4.y, w4.z, w4.w};
      #pragma unroll
      for (int j = 0; j < 4; j++){
        int ff = f + j, vv = ff/3, ii = ff - vv*3;
        V_T[64 + vv][ii*16 + e] = vals2[j];
      }
    }
  }
  __syncthreads();
  { // Q = xv . av, scaled by 1/sqrt3, into A_T rows 130..257
    const int e = t >> 4, l = t & 15;
    const float a0 = av_sh[e][0], a1 = av_sh[e][1], a2 = av_sh[e][2];
    #pragma unroll
    for (int r = 0; r < 8; r++){
      int v = l*8 + r;
      float q = V_T[v][e]*a0 + V_T[v][16+e]*a1 + V_T[v][32+e]*a2;
      A_T[130 + v][e] = q * RSQRT3;
    }
  }

  // ---- m1 ----
  float acc_a[4][2] = {{0.f,0.f},{0.f,0.f},{0.f,0.f},{0.f,0.f}};
  float acc_b[4][2] = {{0.f,0.f},{0.f,0.f},{0.f,0.f},{0.f,0.f}};
  gemm_s<130, 0>(acc_a, Wss1, A_T, W_s, t);
  gemm_s<128, 130>(acc_b, Wvs1, A_T, W_s, t);
  { // s1 = (a_s*(xs@Wss) + (Q/sqrt3)@Wvs)*inv + b
    const int og = t & 31, eg = t >> 5;
    #pragma unroll
    for (int m = 0; m < 2; m++){
      const int e = eg*2 + m;
      const float as = a_s_sh[e];
      #pragma unroll
      for (int j = 0; j < 4; j++){
        const int o = og*4 + j;
        s_buf[e][o] = (as*acc_a[j][m] + acc_b[j][m]) * INV_M1 + b1[o];
      }
    }
  }
  float accT[4] = {0.f,0.f,0.f,0.f};
  gemm_t<130, 0>(accT, Wsv1, A_T, W_s, t);
  float accU[3][4] = {};
  gemm_u<128>(accU, Wvv1, V_T, W_s, t);
  __syncthreads();
  { // m1 epilogue: silu/gate, build m2 inputs in LDS
    const int og = t & 15, e = t >> 4;
    const float as = a_s_sh[e];
    const float a0 = av_sh[e][0], a1 = av_sh[e][1], a2 = av_sh[e][2];
    #pragma unroll
    for (int j = 0; j < 4; j++){
      const int o = og*4 + j;
      const float s1v = s_buf[e][o];
      const float ms = s1v * fast_sigmoid(s1v);
      const float g  = fast_sigmoid(s_buf[e][64+o]);
      const float tt = accT[j];
      const float mv0 = (tt*a0 + as*accU[0][j]) * INV_M1 * g;
      const float mv1 = (tt*a1 + as*accU[1][j]) * INV_M1 * g;
      const float mv2 = (tt*a2 + as*accU[2][j]) * INV_M1 * g;
      A_T[o][e] = ms;                        // m2 xs rows 0..63
      V_T[o][e] = mv0; V_T[o][16+e] = mv1; V_T[o][32+e] = mv2;  // m2 xv
      A_T[64+o][e] = (mv0*a0 + mv1*a1 + mv2*a2) * RSQRT3;       // m2 Q/sqrt3 rows 64..127
    }
  }

  // ---- m2 ----
  #pragma unroll
  for (int j = 0; j < 4; j++){ acc_a[j][0]=0.f; acc_a[j][1]=0.f; acc_b[j][0]=0.f; acc_b[j][1]=0.f; }
  gemm_s<64, 0>(acc_a, Wss2, A_T, W_s, t);
  gemm_s<64, 64>(acc_b, Wvs2, A_T, W_s, t);
  {
    const int og = t & 31, eg = t >> 5;
    #pragma unroll
    for (int m = 0; m < 2; m++){
      const int e = eg*2 + m;
      const float as = a_s_sh[e];
      #pragma unroll
      for (int j = 0; j < 4; j++){
        const int o = og*4 + j;
        s_buf[e][o] = (as*acc_a[j][m] + acc_b[j][m]) * INV_M2 + b2[o];
      }
    }
  }
  #pragma unroll
  for (int j = 0; j < 4; j++) accT[j] = 0.f;
  #pragma unroll
  for (int i = 0; i < 3; i++){ accU[i][0]=0.f; accU[i][1]=0.f; accU[i][2]=0.f; accU[i][3]=0.f; }
  gemm_t<64, 0>(accT, Wsv2, A_T, W_s, t);
  gemm_u<64>(accU, Wvv2, V_T, W_s, t);
  __syncthreads();
  { // final epilogue: gate + atomic scatter into receiver aggregates (out layout: [s(64) | v(192)])
    const int og = t & 15, e = t >> 4;
    const float as = a_s_sh[e];
    const float a0 = av_sh[e][0], a1 = av_sh[e][1], a2 = av_sh[e][2];
    float* base = out + (size_t)rcv_sh[e] * 256;
    #pragma unroll
    for (int j = 0; j < 4; j++){
      const int o = og*4 + j;
      const float s2v = s_buf[e][o];
      atomicAdd(base + o, s2v * fast_sigmoid(s2v));
      const float g = fast_sigmoid(s_buf[e][64+o]);
      const float tt = accT[j];
      atomicAdd(base + 64 + o*3 + 0, (tt*a0 + as*accU[0][j]) * INV_M2 * g);
      atomicAdd(base + 64 + o*3 + 1, (tt*a1 + as*accU[1][j]) * INV_M2 * g);
      atomicAdd(base + 64 + o*3 + 2, (tt*a2 + as*accU[2][j]) * INV_M2 * g);
    }
  }
}

// =================== node kernel: u0 (gated) -> u1 -> residual -> final output ===================
__global__ __launch_bounds__(256, 2) void node_kernel(
    const float* __restrict__ node_s, const float* __restrict__ node_v,
    const float* __restrict__ node_attr_s, const float* __restrict__ node_attr_v,
    const float* __restrict__ Wss0, const float* __restrict__ Wvs0,
    const float* __restrict__ Wsv0, const float* __restrict__ Wvv0,
    const float* __restrict__ b0,
    const float* __restrict__ Wss1, const float* __restrict__ Wvs1,
    const float* __restrict__ Wsv1, const float* __restrict__ Wvv1,
    const float* __restrict__ b1u,
    float* __restrict__ out)
{
  __shared__ float A_T[258][AP];   // rows 0..63 node_s, 64..127 agg_s, 128..255 Q/sqrt3
  __shared__ float V_T[128][VP];   // rows 0..63 node_v, 64..127 agg_v
  __shared__ float W_s[16][WP];
  __shared__ float s_buf[TE][129];
  __shared__ float a_s_sh[TE];
  __shared__ float av_sh[TE][3];

  const int t = threadIdx.x;
  const int n0 = blockIdx.x * TE;

  if (t < TE) a_s_sh[t] = node_attr_s[n0 + t];
  if (t < TE*3) av_sh[t/3][t%3] = node_attr_v[n0*3 + t];
  {
    const int e = t >> 4, l = t & 15;
    const int n = n0 + e;
    float4 v4 = ((const float4*)(node_s + (size_t)n*64))[l];
    A_T[l*4+0][e] = v4.x; A_T[l*4+1][e] = v4.y;
    A_T[l*4+2][e] = v4.z; A_T[l*4+3][e] = v4.w;
    v4 = ((const float4*)(out + (size_t)n*256))[l];           // agg_s
    A_T[64+l*4+0][e] = v4.x; A_T[64+l*4+1][e] = v4.y;
    A_T[64+l*4+2][e] = v4.z; A_T[64+l*4+3][e] = v4.w;
    const float4* pvn = (const float4*)(node_v + (size_t)n*192);
    const float4* pva = (const float4*)(out + (size_t)n*256 + 64);  // agg_v
    #pragma unroll
    for (int q = 0; q < 3; q++){
      float4 w4 = pvn[l*3+q];
      int f = (l*3+q)*4;
      float vals[4] = {w4.x, w4.y, w4.z, w4.w};
      #pragma unroll
      for (int j = 0; j < 4; j++){
        int ff = f + j, vv = ff/3, ii = ff - vv*3;
        V_T[vv][ii*16 + e] = vals[j];
      }
      w4 = pva[l*3+q];
      float vals2[4] = {w4.x, w4.y, w4.z, w4.w};
      #pragma unroll
      for (int j = 0; j < 4; j++){
        int ff = f + j, vv = ff/3, ii = ff - vv*3;
        V_T[64 + vv][ii*16 + e] = vals2[j];
      }
    }
  }
  __syncthreads();
  {
    const int e = t >> 4, l = t & 15;
    const float a0 = av_sh[e][0], a1 = av_sh[e][1], a2 = av_sh[e][2];
    #pragma unroll
    for (int r = 0; r < 8; r++){
      int v = l*8 + r;
      float q = V_T[v][e]*a0 + V_T[v][16+e]*a1 + V_T[v][32+e]*a2;
      A_T[128 + v][e] = q * RSQRT3;
    }
  }

  // ---- u0 (gated) ----
  float acc_a[4][2] = {{0.f,0.f},{0.f,0.f},{0.f,0.f},{0.f,0.f}};
  float acc_b[4][2] = {{0.f,0.f},{0.f,0.f},{0.f,0.f},{0.f,0.f}};
  gemm_s<128, 0>(acc_a, Wss0, A_T, W_s, t);
  gemm_s<128, 128>(acc_b, Wvs0, A_T, W_s, t);
  {
    const int og = t & 31, eg = t >> 5;
    #pragma unroll
    for (int m = 0; m < 2; m++){
      const int e = eg*2 + m;
      const float as = a_s_sh[e];
      #pragma unroll
      for (int j = 0; j < 4; j++){
        const int o = og*4 + j;
        s_buf[e][o] = (as*acc_a[j][m] + acc_b[j][m]) * INV_U0 + b0[o];
      }
    }
  }
  float accT[4] = {0.f,0.f,0.f,0.f};
  gemm_t<128, 0>(accT, Wsv0, A_T, W_s, t);
  float accU[3][4] = {};
  gemm_u<128>(accU, Wvv0, V_T, W_s, t);
  __syncthreads();
  { // u0 epilogue -> hs / hv / Q2 in LDS
    const int og = t & 15, e = t >> 4;
    const float as = a_s_sh[e];
    const float a0 = av_sh[e][0], a1 = av_sh[e][1], a2 = av_sh[e][2];
    #pragma unroll
    for (int j = 0; j < 4; j++){
      const int o = og*4 + j;
      const float s1v = s_buf[e][o];
      const float hs = s1v * fast_sigmoid(s1v);
      const float g  = fast_sigmoid(s_buf[e][64+o]);
      const float tt = accT[j];
      const float hv0 = (tt*a0 + as*accU[0][j]) * INV_U0 * g;
      const float hv1 = (tt*a1 + as*accU[1][j]) * INV_U0 * g;
      const float hv2 = (tt*a2 + as*accU[2][j]) * INV_U0 * g;
      A_T[o][e] = hs;
      V_T[o][e] = hv0; V_T[o][16+e] = hv1; V_T[o][32+e] = hv2;
      A_T[64+o][e] = (hv0*a0 + hv1*a1 + hv2*a2) * RSQRT3;
    }
  }

  // ---- u1 (plain TP, all 64-wide) ----
  float sa[4] = {0.f,0.f,0.f,0.f};
  float sb[4] = {0.f,0.f,0.f,0.f};
  gemm_t<64, 0>(sa, Wss1, A_T, W_s, t);
  gemm_t<64, 64>(sb, Wvs1, A_T, W_s, t);
  float accT2[4] = {0.f,0.f,0.f,0.f};
  gemm_t<64, 0>(accT2, Wsv1, A_T, W_s, t);
  float accU2[3][4] = {};
  gemm_u<64>(accU2, Wvv1, V_T, W_s, t);
  __syncthreads();
  { // final: residual add, overwrite out[n] with [s | v.flat]
    const int og = t & 15, e = t >> 4;
    const int n = n0 + e;
    const float as = a_s_sh[e];
    const float a0 = av_sh[e][0], a1 = av_sh[e][1], a2 = av_sh[e][2];
    #pragma unroll
    for (int j = 0; j < 4; j++){
      const int o = og*4 + j;
      const float us = (as*sa[j] + sb[j]) * INV_U1 + b1u[o];
      out[(size_t)n*256 + o] = node_s[(size_t)n*64 + o] + us;
      const float tt = accT2[j];
      out[(size_t)n*256 + 64 + o*3 + 0] = node_v[(size_t)n*192 + o*3 + 0] + (tt*a0 + as*accU2[0][j]) * INV_U1;
      out[(size_t)n*256 + 64 + o*3 + 1] = node_v[(size_t)n*192 + o*3 + 1] + (tt*a1 + as*accU2[1][j]) * INV_U1;
      out[(size_t)n*256 + 64 + o*3 + 2] = node_v[(size_t)n*192 + o*3 + 2] + (tt*a2 + as*accU2[2][j]) * INV_U1;
    }
  }
}

extern "C" void kernel_launch(void* const* d_in, const int* in_sizes, int n_in,
                              void* d_out, int out_size, void* d_ws, size_t ws_size,
                              hipStream_t stream) {
  const float* node_s      = (const float*)d_in[0];
  const float* node_v      = (const float*)d_in[1];
  const float* node_attr_s = (const float*)d_in[2];
  const float* node_attr_v = (const float*)d_in[3];
  const float* edge_attr_s = (const float*)d_in[4];
  const float* edge_attr_v = (const float*)d_in[5];
  const float* add_feat    = (const float*)d_in[6];
  const float* m1_Wss = (const float*)d_in[7];
  const float* m1_Wvs = (const float*)d_in[8];
  const float* m1_Wsv = (const float*)d_in[9];
  const float* m1_Wvv = (const float*)d_in[10];
  const float* m1_b   = (const float*)d_in[11];
  const float* m2_Wss = (const float*)d_in[12];
  const float* m2_Wvs = (const float*)d_in[13];
  const float* m2_Wsv = (const float*)d_in[14];
  const float* m2_Wvv = (const float*)d_in[15];
  const float* m2_b   = (const float*)d_in[16];
  const float* u0_Wss = (const float*)d_in[17];
  const float* u0_Wvs = (const float*)d_in[18];
  const float* u0_Wsv = (const float*)d_in[19];
  const float* u0_Wvv = (const float*)d_in[20];
  const float* u0_b   = (const float*)d_in[21];
  const float* u1_Wss = (const float*)d_in[22];
  const float* u1_Wvs = (const float*)d_in[23];
  const float* u1_Wsv = (const float*)d_in[24];
  const float* u1_Wvv = (const float*)d_in[25];
  const float* u1_b   = (const float*)d_in[26];
  const int* senders   = (const int*)d_in[27];
  const int* receivers = (const int*)d_in[28];
  float* out = (float*)d_out;

  // out doubles as the aggregation buffer: [agg_s(64) | agg_v(192)] per node
  hipMemsetAsync(d_out, 0, (size_t)out_size * sizeof(float), stream);

  edge_kernel<<<NEDGES / TE, 256, 0, stream>>>(
      node_s, node_v, edge_attr_s, edge_attr_v, add_feat, senders, receivers,
      m1_Wss, m1_Wvs, m1_Wsv, m1_Wvv, m1_b,
      m2_Wss, m2_Wvs, m2_Wsv, m2_Wvv, m2_b, out);

  node_kernel<<<NNODES / TE, 256, 0, stream>>>(
      node_s, node_v, node_attr_s, node_attr_v,
      u0_Wss, u0_Wvs, u0_Wsv, u0_Wvv, u0_b,
      u1_Wss, u1_Wvs, u1_Wsv, u1_Wvv, u1_b, out);
}

// Round 2
// 4354.588 us; speedup vs baseline: 1.1347x; 1.1347x over previous
//
#include <hip/hip_runtime.h>

#define NNODES 50000
#define NEDGES 400000
#define TE 16      // edges (or nodes) per block
#define AP 18      // A_T column pad
#define VP 50      // V_T column pad

constexpr float RSQRT3 = 0.57735026918962576f;
constexpr float INV_M1 = 0.062257280630559f;   // 1/sqrt(130+128)
constexpr float INV_M2 = 0.088388347648318f;   // 1/sqrt(64+64)
constexpr float INV_U0 = 0.0625f;              // 1/sqrt(128+128)
constexpr float INV_U1 = 0.088388347648318f;   // 1/sqrt(64+64)

__device__ __forceinline__ float fast_sigmoid(float x){ return 1.0f / (1.0f + __expf(-x)); }

// ---- GEMM, 128-wide output: W streamed from global (L1/L2-hot), A from LDS ----
// thread: og=t&31 -> 4 cols, eg=t>>5 -> 2 edges. No barriers.
template<int K, int ROWBASE>
__device__ __forceinline__ void gemm_s(float acc[4][2], const float* __restrict__ W,
                                       float (*A_T)[AP], int t){
  const int og = t & 31;
  const int eg = t >> 5;
  const float4* __restrict__ W4 = (const float4*)W;   // row stride 32 float4s
  #pragma unroll 8
  for (int k = 0; k < K; k++){
    const float4 w = W4[k*32 + og];
    const float2 a = *(const float2*)(&A_T[ROWBASE + k][eg*2]);
    acc[0][0] = fmaf(w.x, a.x, acc[0][0]); acc[0][1] = fmaf(w.x, a.y, acc[0][1]);
    acc[1][0] = fmaf(w.y, a.x, acc[1][0]); acc[1][1] = fmaf(w.y, a.y, acc[1][1]);
    acc[2][0] = fmaf(w.z, a.x, acc[2][0]); acc[2][1] = fmaf(w.z, a.y, acc[2][1]);
    acc[3][0] = fmaf(w.w, a.x, acc[3][0]); acc[3][1] = fmaf(w.w, a.y, acc[3][1]);
  }
}

// ---- GEMM, 64-wide output: og=t&15 -> 4 cols, eg=t>>4 -> 1 edge. No barriers. ----
template<int K, int ROWBASE>
__device__ __forceinline__ void gemm_t(float acc[4], const float* __restrict__ W,
                                       float (*A_T)[AP], int t){
  const int og = t & 15;
  const int eg = t >> 4;
  const float4* __restrict__ W4 = (const float4*)W;   // row stride 16 float4s
  #pragma unroll 8
  for (int k = 0; k < K; k++){
    const float4 w = W4[k*16 + og];
    const float a = A_T[ROWBASE + k][eg];
    acc[0] = fmaf(w.x, a, acc[0]); acc[1] = fmaf(w.y, a, acc[1]);
    acc[2] = fmaf(w.z, a, acc[2]); acc[3] = fmaf(w.w, a, acc[3]);
  }
}

// ---- vector-channel GEMM: 3 i-components share the W row. No barriers. ----
template<int K>
__device__ __forceinline__ void gemm_u(float acc[3][4], const float* __restrict__ W,
                                       float (*V_T)[VP], int t){
  const int og = t & 15;
  const int eg = t >> 4;
  const float4* __restrict__ W4 = (const float4*)W;
  #pragma unroll 4
  for (int k = 0; k < K; k++){
    const float4 w = W4[k*16 + og];
    const float a0 = V_T[k][eg], a1 = V_T[k][16+eg], a2 = V_T[k][32+eg];
    acc[0][0] = fmaf(w.x,a0,acc[0][0]); acc[0][1] = fmaf(w.y,a0,acc[0][1]);
    acc[0][2] = fmaf(w.z,a0,acc[0][2]); acc[0][3] = fmaf(w.w,a0,acc[0][3]);
    acc[1][0] = fmaf(w.x,a1,acc[1][0]); acc[1][1] = fmaf(w.y,a1,acc[1][1]);
    acc[1][2] = fmaf(w.z,a1,acc[1][2]); acc[1][3] = fmaf(w.w,a1,acc[1][3]);
    acc[2][0] = fmaf(w.x,a2,acc[2][0]); acc[2][1] = fmaf(w.y,a2,acc[2][1]);
    acc[2][2] = fmaf(w.z,a2,acc[2][2]); acc[2][3] = fmaf(w.w,a2,acc[2][3]);
  }
}

// =================== edge kernel: m1 (gated) -> m2 (gated) -> atomic aggregate ===================
__global__ __launch_bounds__(256, 3) void edge_kernel(
    const float* __restrict__ node_s, const float* __restrict__ node_v,
    const float* __restrict__ edge_attr_s, const float* __restrict__ edge_attr_v,
    const float* __restrict__ add_feat,
    const int* __restrict__ senders, const int* __restrict__ receivers,
    const float* __restrict__ Wss1, const float* __restrict__ Wvs1,
    const float* __restrict__ Wsv1, const float* __restrict__ Wvv1,
    const float* __restrict__ b1,
    const float* __restrict__ Wss2, const float* __restrict__ Wvs2,
    const float* __restrict__ Wsv2, const float* __restrict__ Wvv2,
    const float* __restrict__ b2,
    float* __restrict__ out)
{
  __shared__ float A_T[258][AP];   // m1: rows 0..129 = xs, 130..257 = Q/sqrt3; m2 reuses rows 0..127
  __shared__ float V_T[128][VP];   // raw xv (col = i*16+e); rows 0..63 reused for gated mv
  __shared__ float s_buf[TE][129];
  __shared__ float a_s_sh[TE];
  __shared__ float av_sh[TE][3];
  __shared__ int snd_sh[TE];
  __shared__ int rcv_sh[TE];

  const int t = threadIdx.x;
  const int e0 = blockIdx.x * TE;

  if (t < TE){
    a_s_sh[t] = edge_attr_s[e0 + t];
    snd_sh[t] = senders[e0 + t];
    rcv_sh[t] = receivers[e0 + t];
  }
  if (t < TE*3){
    av_sh[t/3][t%3] = edge_attr_v[e0*3 + t];
  }
  __syncthreads();   // B1: indices/attrs ready

  { // stage xs / xv for 16 edges (16 threads per edge, float4 gathers)
    const int e = t >> 4, l = t & 15;
    const int snd = snd_sh[e], rcv = rcv_sh[e];
    float4 v4 = ((const float4*)(node_s + (size_t)snd*64))[l];
    A_T[l*4+0][e] = v4.x; A_T[l*4+1][e] = v4.y;
    A_T[l*4+2][e] = v4.z; A_T[l*4+3][e] = v4.w;
    v4 = ((const float4*)(node_s + (size_t)rcv*64))[l];
    A_T[64+l*4+0][e] = v4.x; A_T[64+l*4+1][e] = v4.y;
    A_T[64+l*4+2][e] = v4.z; A_T[64+l*4+3][e] = v4.w;
    if (l == 0){
      A_T[128][e] = add_feat[(e0+e)*2 + 0];
      A_T[129][e] = add_feat[(e0+e)*2 + 1];
    }
    const float4* pvs = (const float4*)(node_v + (size_t)snd*192);
    const float4* pvr = (const float4*)(node_v + (size_t)rcv*192);
    #pragma unroll
    for (int q = 0; q < 3; q++){
      float4 w4 = pvs[l*3+q];
      int f = (l*3+q)*4;
      float vals[4] = {w4.x, w4.y, w4.z, w4.w};
      #pragma unroll
      for (int j = 0; j < 4; j++){
        int ff = f + j, vv = ff/3, ii = ff - vv*3;
        V_T[vv][ii*16 + e] = vals[j];
      }
      w4 = pvr[l*3+q];
      float vals2[4] = {w4.x, w4.y, w4.z, w4.w};
      #pragma unroll
      for (int j = 0; j < 4; j++){
        int ff = f + j, vv = ff/3, ii = ff - vv*3;
        V_T[64 + vv][ii*16 + e] = vals2[j];
      }
    }
  }
  __syncthreads();   // B2: A_T/V_T staged
  { // Q = xv . av, scaled by 1/sqrt3, into A_T rows 130..257
    const int e = t >> 4, l = t & 15;
    const float a0 = av_sh[e][0], a1 = av_sh[e][1], a2 = av_sh[e][2];
    #pragma unroll
    for (int r = 0; r < 8; r++){
      int v = l*8 + r;
      float q = V_T[v][e]*a0 + V_T[v][16+e]*a1 + V_T[v][32+e]*a2;
      A_T[130 + v][e] = q * RSQRT3;
    }
  }
  __syncthreads();   // B3: Q rows ready

  // ---- m1 ----
  float acc_a[4][2] = {{0.f,0.f},{0.f,0.f},{0.f,0.f},{0.f,0.f}};
  float acc_b[4][2] = {{0.f,0.f},{0.f,0.f},{0.f,0.f},{0.f,0.f}};
  gemm_s<130, 0>(acc_a, Wss1, A_T, t);
  gemm_s<128, 130>(acc_b, Wvs1, A_T, t);
  { // s1 = (a_s*(xs@Wss) + (Q/sqrt3)@Wvs)*inv + b
    const int og = t & 31, eg = t >> 5;
    #pragma unroll
    for (int m = 0; m < 2; m++){
      const int e = eg*2 + m;
      const float as = a_s_sh[e];
      #pragma unroll
      for (int j = 0; j < 4; j++){
        const int o = og*4 + j;
        s_buf[e][o] = (as*acc_a[j][m] + acc_b[j][m]) * INV_M1 + b1[o];
      }
    }
  }
  float accT[4] = {0.f,0.f,0.f,0.f};
  gemm_t<130, 0>(accT, Wsv1, A_T, t);
  float accU[3][4] = {};
  gemm_u<128>(accU, Wvv1, V_T, t);
  __syncthreads();   // B4: all m1 reads of A_T/V_T/s_buf-writes done
  { // m1 epilogue: silu/gate, build m2 inputs in LDS
    const int og = t & 15, e = t >> 4;
    const float as = a_s_sh[e];
    const float a0 = av_sh[e][0], a1 = av_sh[e][1], a2 = av_sh[e][2];
    #pragma unroll
    for (int j = 0; j < 4; j++){
      const int o = og*4 + j;
      const float s1v = s_buf[e][o];
      const float ms = s1v * fast_sigmoid(s1v);
      const float g  = fast_sigmoid(s_buf[e][64+o]);
      const float tt = accT[j];
      const float mv0 = (tt*a0 + as*accU[0][j]) * INV_M1 * g;
      const float mv1 = (tt*a1 + as*accU[1][j]) * INV_M1 * g;
      const float mv2 = (tt*a2 + as*accU[2][j]) * INV_M1 * g;
      A_T[o][e] = ms;                        // m2 xs rows 0..63
      V_T[o][e] = mv0; V_T[o][16+e] = mv1; V_T[o][32+e] = mv2;  // m2 xv
      A_T[64+o][e] = (mv0*a0 + mv1*a1 + mv2*a2) * RSQRT3;       // m2 Q/sqrt3 rows 64..127
    }
  }
  __syncthreads();   // B5: m2 inputs ready

  // ---- m2 ----
  #pragma unroll
  for (int j = 0; j < 4; j++){ acc_a[j][0]=0.f; acc_a[j][1]=0.f; acc_b[j][0]=0.f; acc_b[j][1]=0.f; }
  gemm_s<64, 0>(acc_a, Wss2, A_T, t);
  gemm_s<64, 64>(acc_b, Wvs2, A_T, t);
  {
    const int og = t & 31, eg = t >> 5;
    #pragma unroll
    for (int m = 0; m < 2; m++){
      const int e = eg*2 + m;
      const float as = a_s_sh[e];
      #pragma unroll
      for (int j = 0; j < 4; j++){
        const int o = og*4 + j;
        s_buf[e][o] = (as*acc_a[j][m] + acc_b[j][m]) * INV_M2 + b2[o];
      }
    }
  }
  #pragma unroll
  for (int j = 0; j < 4; j++) accT[j] = 0.f;
  #pragma unroll
  for (int i = 0; i < 3; i++){ accU[i][0]=0.f; accU[i][1]=0.f; accU[i][2]=0.f; accU[i][3]=0.f; }
  gemm_t<64, 0>(accT, Wsv2, A_T, t);
  gemm_u<64>(accU, Wvv2, V_T, t);
  __syncthreads();   // B6: s_buf (m2) ready
  { // final epilogue: gate + atomic scatter into receiver aggregates (out layout: [s(64) | v(192)])
    const int og = t & 15, e = t >> 4;
    const float as = a_s_sh[e];
    const float a0 = av_sh[e][0], a1 = av_sh[e][1], a2 = av_sh[e][2];
    float* base = out + (size_t)rcv_sh[e] * 256;
    #pragma unroll
    for (int j = 0; j < 4; j++){
      const int o = og*4 + j;
      const float s2v = s_buf[e][o];
      atomicAdd(base + o, s2v * fast_sigmoid(s2v));
      const float g = fast_sigmoid(s_buf[e][64+o]);
      const float tt = accT[j];
      atomicAdd(base + 64 + o*3 + 0, (tt*a0 + as*accU[0][j]) * INV_M2 * g);
      atomicAdd(base + 64 + o*3 + 1, (tt*a1 + as*accU[1][j]) * INV_M2 * g);
      atomicAdd(base + 64 + o*3 + 2, (tt*a2 + as*accU[2][j]) * INV_M2 * g);
    }
  }
}

// =================== node kernel: u0 (gated) -> u1 -> residual -> final output ===================
__global__ __launch_bounds__(256, 3) void node_kernel(
    const float* __restrict__ node_s, const float* __restrict__ node_v,
    const float* __restrict__ node_attr_s, const float* __restrict__ node_attr_v,
    const float* __restrict__ Wss0, const float* __restrict__ Wvs0,
    const float* __restrict__ Wsv0, const float* __restrict__ Wvv0,
    const float* __restrict__ b0,
    const float* __restrict__ Wss1, const float* __restrict__ Wvs1,
    const float* __restrict__ Wsv1, const float* __restrict__ Wvv1,
    const float* __restrict__ b1u,
    float* __restrict__ out)
{
  __shared__ float A_T[256][AP];   // rows 0..63 node_s, 64..127 agg_s, 128..255 Q/sqrt3
  __shared__ float V_T[128][VP];   // rows 0..63 node_v, 64..127 agg_v
  __shared__ float s_buf[TE][129];
  __shared__ float a_s_sh[TE];
  __shared__ float av_sh[TE][3];

  const int t = threadIdx.x;
  const int n0 = blockIdx.x * TE;

  if (t < TE) a_s_sh[t] = node_attr_s[n0 + t];
  if (t < TE*3) av_sh[t/3][t%3] = node_attr_v[n0*3 + t];
  {
    const int e = t >> 4, l = t & 15;
    const int n = n0 + e;
    float4 v4 = ((const float4*)(node_s + (size_t)n*64))[l];
    A_T[l*4+0][e] = v4.x; A_T[l*4+1][e] = v4.y;
    A_T[l*4+2][e] = v4.z; A_T[l*4+3][e] = v4.w;
    v4 = ((const float4*)(out + (size_t)n*256))[l];           // agg_s
    A_T[64+l*4+0][e] = v4.x; A_T[64+l*4+1][e] = v4.y;
    A_T[64+l*4+2][e] = v4.z; A_T[64+l*4+3][e] = v4.w;
    const float4* pvn = (const float4*)(node_v + (size_t)n*192);
    const float4* pva = (const float4*)(out + (size_t)n*256 + 64);  // agg_v
    #pragma unroll
    for (int q = 0; q < 3; q++){
      float4 w4 = pvn[l*3+q];
      int f = (l*3+q)*4;
      float vals[4] = {w4.x, w4.y, w4.z, w4.w};
      #pragma unroll
      for (int j = 0; j < 4; j++){
        int ff = f + j, vv = ff/3, ii = ff - vv*3;
        V_T[vv][ii*16 + e] = vals[j];
      }
      w4 = pva[l*3+q];
      float vals2[4] = {w4.x, w4.y, w4.z, w4.w};
      #pragma unroll
      for (int j = 0; j < 4; j++){
        int ff = f + j, vv = ff/3, ii = ff - vv*3;
        V_T[64 + vv][ii*16 + e] = vals2[j];
      }
    }
  }
  __syncthreads();   // B2: staged
  {
    const int e = t >> 4, l = t & 15;
    const float a0 = av_sh[e][0], a1 = av_sh[e][1], a2 = av_sh[e][2];
    #pragma unroll
    for (int r = 0; r < 8; r++){
      int v = l*8 + r;
      float q = V_T[v][e]*a0 + V_T[v][16+e]*a1 + V_T[v][32+e]*a2;
      A_T[128 + v][e] = q * RSQRT3;
    }
  }
  __syncthreads();   // B3: Q ready

  // ---- u0 (gated) ----
  float acc_a[4][2] = {{0.f,0.f},{0.f,0.f},{0.f,0.f},{0.f,0.f}};
  float acc_b[4][2] = {{0.f,0.f},{0.f,0.f},{0.f,0.f},{0.f,0.f}};
  gemm_s<128, 0>(acc_a, Wss0, A_T, t);
  gemm_s<128, 128>(acc_b, Wvs0, A_T, t);
  {
    const int og = t & 31, eg = t >> 5;
    #pragma unroll
    for (int m = 0; m < 2; m++){
      const int e = eg*2 + m;
      const float as = a_s_sh[e];
      #pragma unroll
      for (int j = 0; j < 4; j++){
        const int o = og*4 + j;
        s_buf[e][o] = (as*acc_a[j][m] + acc_b[j][m]) * INV_U0 + b0[o];
      }
    }
  }
  float accT[4] = {0.f,0.f,0.f,0.f};
  gemm_t<128, 0>(accT, Wsv0, A_T, t);
  float accU[3][4] = {};
  gemm_u<128>(accU, Wvv0, V_T, t);
  __syncthreads();   // B4
  { // u0 epilogue -> hs / hv / Q2 in LDS
    const int og = t & 15, e = t >> 4;
    const float as = a_s_sh[e];
    const float a0 = av_sh[e][0], a1 = av_sh[e][1], a2 = av_sh[e][2];
    #pragma unroll
    for (int j = 0; j < 4; j++){
      const int o = og*4 + j;
      const float s1v = s_buf[e][o];
      const float hs = s1v * fast_sigmoid(s1v);
      const float g  = fast_sigmoid(s_buf[e][64+o]);
      const float tt = accT[j];
      const float hv0 = (tt*a0 + as*accU[0][j]) * INV_U0 * g;
      const float hv1 = (tt*a1 + as*accU[1][j]) * INV_U0 * g;
      const float hv2 = (tt*a2 + as*accU[2][j]) * INV_U0 * g;
      A_T[o][e] = hs;
      V_T[o][e] = hv0; V_T[o][16+e] = hv1; V_T[o][32+e] = hv2;
      A_T[64+o][e] = (hv0*a0 + hv1*a1 + hv2*a2) * RSQRT3;
    }
  }
  __syncthreads();   // B5: u1 inputs ready

  // ---- u1 (plain TP, all 64-wide) ----
  float sa[4] = {0.f,0.f,0.f,0.f};
  float sb[4] = {0.f,0.f,0.f,0.f};
  gemm_t<64, 0>(sa, Wss1, A_T, t);
  gemm_t<64, 64>(sb, Wvs1, A_T, t);
  float accT2[4] = {0.f,0.f,0.f,0.f};
  gemm_t<64, 0>(accT2, Wsv1, A_T, t);
  float accU2[3][4] = {};
  gemm_u<64>(accU2, Wvv1, V_T, t);
  // all u1 results live in registers with matching (og,e) mapping -> no barrier needed
  { // final: residual add, overwrite out[n] with [s | v.flat]
    const int og = t & 15, e = t >> 4;
    const int n = n0 + e;
    const float as = a_s_sh[e];
    const float a0 = av_sh[e][0], a1 = av_sh[e][1], a2 = av_sh[e][2];
    #pragma unroll
    for (int j = 0; j < 4; j++){
      const int o = og*4 + j;
      const float us = (as*sa[j] + sb[j]) * INV_U1 + b1u[o];
      out[(size_t)n*256 + o] = node_s[(size_t)n*64 + o] + us;
      const float tt = accT2[j];
      out[(size_t)n*256 + 64 + o*3 + 0] = node_v[(size_t)n*192 + o*3 + 0] + (tt*a0 + as*accU2[0][j]) * INV_U1;
      out[(size_t)n*256 + 64 + o*3 + 1] = node_v[(size_t)n*192 + o*3 + 1] + (tt*a1 + as*accU2[1][j]) * INV_U1;
      out[(size_t)n*256 + 64 + o*3 + 2] = node_v[(size_t)n*192 + o*3 + 2] + (tt*a2 + as*accU2[2][j]) * INV_U1;
    }
  }
}

extern "C" void kernel_launch(void* const* d_in, const int* in_sizes, int n_in,
                              void* d_out, int out_size, void* d_ws, size_t ws_size,
                              hipStream_t stream) {
  const float* node_s      = (const float*)d_in[0];
  const float* node_v      = (const float*)d_in[1];
  const float* node_attr_s = (const float*)d_in[2];
  const float* node_attr_v = (const float*)d_in[3];
  const float* edge_attr_s = (const float*)d_in[4];
  const float* edge_attr_v = (const float*)d_in[5];
  const float* add_feat    = (const float*)d_in[6];
  const float* m1_Wss = (const float*)d_in[7];
  const float* m1_Wvs = (const float*)d_in[8];
  const float* m1_Wsv = (const float*)d_in[9];
  const float* m1_Wvv = (const float*)d_in[10];
  const float* m1_b   = (const float*)d_in[11];
  const float* m2_Wss = (const float*)d_in[12];
  const float* m2_Wvs = (const float*)d_in[13];
  const float* m2_Wsv = (const float*)d_in[14];
  const float* m2_Wvv = (const float*)d_in[15];
  const float* m2_b   = (const float*)d_in[16];
  const float* u0_Wss = (const float*)d_in[17];
  const float* u0_Wvs = (const float*)d_in[18];
  const float* u0_Wsv = (const float*)d_in[19];
  const float* u0_Wvv = (const float*)d_in[20];
  const float* u0_b   = (const float*)d_in[21];
  const float* u1_Wss = (const float*)d_in[22];
  const float* u1_Wvs = (const float*)d_in[23];
  const float* u1_Wsv = (const float*)d_in[24];
  const float* u1_Wvv = (const float*)d_in[25];
  const float* u1_b   = (const float*)d_in[26];
  const int* senders   = (const int*)d_in[27];
  const int* receivers = (const int*)d_in[28];
  float* out = (float*)d_out;

  // out doubles as the aggregation buffer: [agg_s(64) | agg_v(192)] per node
  hipMemsetAsync(d_out, 0, (size_t)out_size * sizeof(float), stream);

  edge_kernel<<<NEDGES / TE, 256, 0, stream>>>(
      node_s, node_v, edge_attr_s, edge_attr_v, add_feat, senders, receivers,
      m1_Wss, m1_Wvs, m1_Wsv, m1_Wvv, m1_b,
      m2_Wss, m2_Wvs, m2_Wsv, m2_Wvv, m2_b, out);

  node_kernel<<<NNODES / TE, 256, 0, stream>>>(
      node_s, node_v, node_attr_s, node_attr_v,
      u0_Wss, u0_Wvs, u0_Wsv, u0_Wvv, u0_b,
      u1_Wss, u1_Wvs, u1_Wsv, u1_Wvv, u1_b, out);
}

// Round 3
// 4197.385 us; speedup vs baseline: 1.1772x; 1.0375x over previous
//
#include <hip/hip_runtime.h>

#define NNODES 50000
#define NEDGES 400000

// ---- node-kernel tile params (round-2 structure, unchanged) ----
#define TE 16
#define AP 18
#define VP 50

// ---- edge-kernel params ----
#define ET 64      // edges per block
#define QW 68      // Q / msT row stride (float4-aligned: 68*4=272 bytes)
#define SW 132     // sbuf row stride (132*4=528, 16B-aligned)
#define VW 194     // V row stride (float2-aligned)

constexpr float RSQRT3 = 0.57735026918962576f;
constexpr float INV_M1 = 0.062257280630559f;   // 1/sqrt(130+128)
constexpr float INV_M2 = 0.088388347648318f;   // 1/sqrt(64+64)
constexpr float INV_U0 = 0.0625f;              // 1/sqrt(128+128)
constexpr float INV_U1 = 0.088388347648318f;   // 1/sqrt(64+64)

__device__ __forceinline__ float fast_sigmoid(float x){ return 1.0f / (1.0f + __expf(-x)); }

// =====================================================================
// EDGE KERNEL: 64 edges / 512 threads. m1 (gated) -> m2 (gated) -> atomic agg.
// W streamed from global (coalesced float4, L2-hot); A/V staged in LDS K-tiles.
// =====================================================================
__global__ __launch_bounds__(512, 2) void edge_kernel(
    const float* __restrict__ node_s, const float* __restrict__ node_v,
    const float* __restrict__ edge_attr_s, const float* __restrict__ edge_attr_v,
    const float* __restrict__ add_feat,
    const int* __restrict__ senders, const int* __restrict__ receivers,
    const float* __restrict__ Wss1, const float* __restrict__ Wvs1,
    const float* __restrict__ Wsv1, const float* __restrict__ Wvv1,
    const float* __restrict__ b1,
    const float* __restrict__ Wss2, const float* __restrict__ Wvs2,
    const float* __restrict__ Wsv2, const float* __restrict__ Wvv2,
    const float* __restrict__ b2,
    float* __restrict__ out)
{
  // LDS regions (total ~120 KB -> 1 block/CU, 8 waves)
  __shared__ __align__(16) float Qreg[128][QW];  // phase1-3: Q ; after epi-1: msT(rows 0..63)+Q2T(64..127)
  __shared__ __align__(16) float sbuf[ET][SW];   // s1 then s2 (cross-thread handoff)
  __shared__ __align__(16) float VC[ET][VW];     // phase1: Vt[32][VW]; phase2: A2[32][QW] view; m2: V2[64][VW]
  __shared__ __align__(16) float af_sh[2][QW];
  __shared__ float as_sh[ET], av0_sh[ET], av1_sh[ET], av2_sh[ET];
  __shared__ int snd_sh[ET], rcv_sh[ET];

  const int t   = threadIdx.x;
  const int e0  = blockIdx.x * ET;
  const int og5 = t & 31, eg5 = t >> 5;   // 128-wide mapping: 4 cols x 4 edges
  const int og4 = t & 15, eg4 = t >> 4;   // 64-wide mapping:  4 cols x 2 edges

  // ---- stage attrs / indices ----
  if (t < ET){
    as_sh[t]  = edge_attr_s[e0 + t];
    snd_sh[t] = senders[e0 + t];
    rcv_sh[t] = receivers[e0 + t];
  } else if (t < 2*ET){
    const int e = t - ET;
    av0_sh[e] = edge_attr_v[(size_t)(e0+e)*3 + 0];
    av1_sh[e] = edge_attr_v[(size_t)(e0+e)*3 + 1];
    av2_sh[e] = edge_attr_v[(size_t)(e0+e)*3 + 2];
  } else if (t < 2*ET + 2*ET){
    const int x = t - 2*ET, e = x >> 1, d = x & 1;
    af_sh[d][e] = add_feat[(size_t)(e0+e)*2 + d];
  }
  __syncthreads();

  // ================= phase 1: V-tiles -> gemm_u(Wvv1) + build Q =================
  float accU[3][4][2] = {};
  for (int kt = 0; kt < 4; kt++){
    { // stage 32 K-rows of V (and Q rows) for all 64 edges
      const int e = t >> 3, q = t & 7;
      const int n = (kt < 2) ? snd_sh[e] : rcv_sh[e];
      const float4* src = (const float4*)(node_v + (size_t)n*192) + (kt & 1)*24 + q*3;
      float4 f0 = src[0], f1 = src[1], f2 = src[2];
      float f[12] = {f0.x,f0.y,f0.z,f0.w, f1.x,f1.y,f1.z,f1.w, f2.x,f2.y,f2.z,f2.w};
      const float a0 = av0_sh[e], a1 = av1_sh[e], a2 = av2_sh[e];
      #pragma unroll
      for (int d = 0; d < 4; d++){
        const int r = q*4 + d;
        VC[r][0*64 + e] = f[d*3+0];
        VC[r][1*64 + e] = f[d*3+1];
        VC[r][2*64 + e] = f[d*3+2];
        Qreg[kt*32 + r][e] = (f[d*3]*a0 + f[d*3+1]*a1 + f[d*3+2]*a2) * RSQRT3;
      }
    }
    __syncthreads();
    const float4* W4 = (const float4*)Wvv1 + (size_t)(kt*32)*16 + og4;
    #pragma unroll 4
    for (int r = 0; r < 32; r++){
      const float4 wv = W4[(size_t)r*16];
      const float w[4] = {wv.x, wv.y, wv.z, wv.w};
      const float2 a0 = *(const float2*)&VC[r][0*64 + eg4*2];
      const float2 a1 = *(const float2*)&VC[r][1*64 + eg4*2];
      const float2 a2 = *(const float2*)&VC[r][2*64 + eg4*2];
      const float av0a[2] = {a0.x, a0.y}, av1a[2] = {a1.x, a1.y}, av2a[2] = {a2.x, a2.y};
      #pragma unroll
      for (int j = 0; j < 4; j++){
        #pragma unroll
        for (int m = 0; m < 2; m++){
          accU[0][j][m] = fmaf(w[j], av0a[m], accU[0][j][m]);
          accU[1][j][m] = fmaf(w[j], av1a[m], accU[1][j][m]);
          accU[2][j][m] = fmaf(w[j], av2a[m], accU[2][j][m]);
        }
      }
    }
    __syncthreads();
  }

  // ================= phase 2: xs-tiles -> gemm_s(Wss1) + gemm_t(Wsv1) =================
  float accS[4][4] = {};
  float accT[4][2] = {};
  float (*A2)[QW] = (float(*)[QW])VC;   // [32][68] view (16B-aligned rows)
  for (int kt = 0; kt < 4; kt++){
    {
      const int e = t >> 3, q = t & 7;
      const int n = (kt < 2) ? snd_sh[e] : rcv_sh[e];
      const float4 f = ((const float4*)(node_s + (size_t)n*64))[(kt & 1)*8 + q];
      A2[q*4+0][e] = f.x; A2[q*4+1][e] = f.y; A2[q*4+2][e] = f.z; A2[q*4+3][e] = f.w;
    }
    __syncthreads();
    const float4* Wa = (const float4*)Wss1 + (size_t)(kt*32)*32 + og5;
    const float4* Wb = (const float4*)Wsv1 + (size_t)(kt*32)*16 + og4;
    #pragma unroll 4
    for (int r = 0; r < 32; r++){
      const float4 wav = Wa[(size_t)r*32];
      const float wa[4] = {wav.x, wav.y, wav.z, wav.w};
      const float4 a4 = *(const float4*)&A2[r][eg5*4];
      const float aa[4] = {a4.x, a4.y, a4.z, a4.w};
      #pragma unroll
      for (int j = 0; j < 4; j++)
        #pragma unroll
        for (int m = 0; m < 4; m++)
          accS[j][m] = fmaf(wa[j], aa[m], accS[j][m]);
      const float4 wbv = Wb[(size_t)r*16];
      const float wb[4] = {wbv.x, wbv.y, wbv.z, wbv.w};
      const float2 a2v = *(const float2*)&A2[r][eg4*2];
      const float ab[2] = {a2v.x, a2v.y};
      #pragma unroll
      for (int j = 0; j < 4; j++)
        #pragma unroll
        for (int m = 0; m < 2; m++)
          accT[j][m] = fmaf(wb[j], ab[m], accT[j][m]);
    }
    __syncthreads();
  }
  // tail rows 128..129 (add_feat)
  #pragma unroll
  for (int d = 0; d < 2; d++){
    const float4 wav = ((const float4*)Wss1)[(size_t)(128+d)*32 + og5];
    const float wa[4] = {wav.x, wav.y, wav.z, wav.w};
    const float4 a4 = *(const float4*)&af_sh[d][eg5*4];
    const float aa[4] = {a4.x, a4.y, a4.z, a4.w};
    #pragma unroll
    for (int j = 0; j < 4; j++)
      #pragma unroll
      for (int m = 0; m < 4; m++)
        accS[j][m] = fmaf(wa[j], aa[m], accS[j][m]);
    const float4 wbv = ((const float4*)Wsv1)[(size_t)(128+d)*16 + og4];
    const float wb[4] = {wbv.x, wbv.y, wbv.z, wbv.w};
    const float ab[2] = {af_sh[d][eg4*2], af_sh[d][eg4*2+1]};
    #pragma unroll
    for (int j = 0; j < 4; j++)
      #pragma unroll
      for (int m = 0; m < 2; m++)
        accT[j][m] = fmaf(wb[j], ab[m], accT[j][m]);
  }

  // ================= phase 3: gemm_s(Wvs1) over resident Q (no barriers) =================
  float accV[4][4] = {};
  {
    const float4* Wc = (const float4*)Wvs1 + og5;
    #pragma unroll 4
    for (int k = 0; k < 128; k++){
      const float4 wv = Wc[(size_t)k*32];
      const float w[4] = {wv.x, wv.y, wv.z, wv.w};
      const float4 a4 = *(const float4*)&Qreg[k][eg5*4];
      const float aa[4] = {a4.x, a4.y, a4.z, a4.w};
      #pragma unroll
      for (int j = 0; j < 4; j++)
        #pragma unroll
        for (int m = 0; m < 4; m++)
          accV[j][m] = fmaf(w[j], aa[m], accV[j][m]);
    }
  }
  { // s1 -> sbuf
    const float4 b1v = ((const float4*)b1)[og5];
    const float bb[4] = {b1v.x, b1v.y, b1v.z, b1v.w};
    #pragma unroll
    for (int m = 0; m < 4; m++){
      const int e = eg5*4 + m;
      const float as = as_sh[e];
      float4 s1;
      s1.x = (as*accS[0][m] + accV[0][m]) * INV_M1 + bb[0];
      s1.y = (as*accS[1][m] + accV[1][m]) * INV_M1 + bb[1];
      s1.z = (as*accS[2][m] + accV[2][m]) * INV_M1 + bb[2];
      s1.w = (as*accS[3][m] + accV[3][m]) * INV_M1 + bb[3];
      *(float4*)&sbuf[e][og5*4] = s1;
    }
  }
  __syncthreads();

  // ================= m1 epilogue: gate, build m2 inputs (msT/Q2T/V2) =================
  {
    #pragma unroll
    for (int m = 0; m < 2; m++){
      const int e = eg4*2 + m;
      const float as = as_sh[e];
      const float a0 = av0_sh[e], a1 = av1_sh[e], a2 = av2_sh[e];
      #pragma unroll
      for (int j = 0; j < 4; j++){
        const int o = og4*4 + j;
        const float s1a = sbuf[e][o];
        const float s1b = sbuf[e][64 + o];
        const float ms = s1a * fast_sigmoid(s1a);
        const float g  = fast_sigmoid(s1b);
        const float tt = accT[j][m];
        const float mv0 = (tt*a0 + as*accU[0][j][m]) * INV_M1 * g;
        const float mv1 = (tt*a1 + as*accU[1][j][m]) * INV_M1 * g;
        const float mv2 = (tt*a2 + as*accU[2][j][m]) * INV_M1 * g;
        Qreg[o][e]      = ms;                                      // msT rows 0..63
        Qreg[64 + o][e] = (mv0*a0 + mv1*a1 + mv2*a2) * RSQRT3;     // Q2T rows 64..127
        VC[o][0*64 + e] = mv0; VC[o][1*64 + e] = mv1; VC[o][2*64 + e] = mv2;  // V2
      }
    }
  }
  __syncthreads();

  // ================= m2: all inputs LDS-resident, K=64 each =================
  float acc2S[4][4] = {};
  {
    const float4* Wd = (const float4*)Wss2 + og5;
    #pragma unroll 4
    for (int k = 0; k < 64; k++){
      const float4 wv = Wd[(size_t)k*32];
      const float w[4] = {wv.x, wv.y, wv.z, wv.w};
      const float4 a4 = *(const float4*)&Qreg[k][eg5*4];
      const float aa[4] = {a4.x, a4.y, a4.z, a4.w};
      #pragma unroll
      for (int j = 0; j < 4; j++)
        #pragma unroll
        for (int m = 0; m < 4; m++)
          acc2S[j][m] = fmaf(w[j], aa[m], acc2S[j][m]);
    }
  }
  float acc2V[4][4] = {};
  {
    const float4* We = (const float4*)Wvs2 + og5;
    #pragma unroll 4
    for (int k = 0; k < 64; k++){
      const float4 wv = We[(size_t)k*32];
      const float w[4] = {wv.x, wv.y, wv.z, wv.w};
      const float4 a4 = *(const float4*)&Qreg[64 + k][eg5*4];
      const float aa[4] = {a4.x, a4.y, a4.z, a4.w};
      #pragma unroll
      for (int j = 0; j < 4; j++)
        #pragma unroll
        for (int m = 0; m < 4; m++)
          acc2V[j][m] = fmaf(w[j], aa[m], acc2V[j][m]);
    }
  }
  { // s2 -> sbuf (epilogue-1 reads finished at last barrier)
    const float4 b2v = ((const float4*)b2)[og5];
    const float bb[4] = {b2v.x, b2v.y, b2v.z, b2v.w};
    #pragma unroll
    for (int m = 0; m < 4; m++){
      const int e = eg5*4 + m;
      const float as = as_sh[e];
      float4 s2;
      s2.x = (as*acc2S[0][m] + acc2V[0][m]) * INV_M2 + bb[0];
      s2.y = (as*acc2S[1][m] + acc2V[1][m]) * INV_M2 + bb[1];
      s2.z = (as*acc2S[2][m] + acc2V[2][m]) * INV_M2 + bb[2];
      s2.w = (as*acc2S[3][m] + acc2V[3][m]) * INV_M2 + bb[3];
      *(float4*)&sbuf[e][og5*4] = s2;
    }
  }
  float acc2T[4][2] = {};
  {
    const float4* Wf = (const float4*)Wsv2 + og4;
    #pragma unroll 4
    for (int k = 0; k < 64; k++){
      const float4 wv = Wf[(size_t)k*16];
      const float w[4] = {wv.x, wv.y, wv.z, wv.w};
      const float2 a2v = *(const float2*)&Qreg[k][eg4*2];
      const float aa[2] = {a2v.x, a2v.y};
      #pragma unroll
      for (int j = 0; j < 4; j++)
        #pragma unroll
        for (int m = 0; m < 2; m++)
          acc2T[j][m] = fmaf(w[j], aa[m], acc2T[j][m]);
    }
  }
  float acc2U[3][4][2] = {};
  {
    const float4* Wg = (const float4*)Wvv2 + og4;
    #pragma unroll 4
    for (int k = 0; k < 64; k++){
      const float4 wv = Wg[(size_t)k*16];
      const float w[4] = {wv.x, wv.y, wv.z, wv.w};
      const float2 a0 = *(const float2*)&VC[k][0*64 + eg4*2];
      const float2 a1 = *(const float2*)&VC[k][1*64 + eg4*2];
      const float2 a2 = *(const float2*)&VC[k][2*64 + eg4*2];
      const float av0a[2] = {a0.x, a0.y}, av1a[2] = {a1.x, a1.y}, av2a[2] = {a2.x, a2.y};
      #pragma unroll
      for (int j = 0; j < 4; j++)
        #pragma unroll
        for (int m = 0; m < 2; m++){
          acc2U[0][j][m] = fmaf(w[j], av0a[m], acc2U[0][j][m]);
          acc2U[1][j][m] = fmaf(w[j], av1a[m], acc2U[1][j][m]);
          acc2U[2][j][m] = fmaf(w[j], av2a[m], acc2U[2][j][m]);
        }
    }
  }
  __syncthreads();

  // ================= final epilogue: gate + atomic scatter =================
  {
    #pragma unroll
    for (int m = 0; m < 2; m++){
      const int e = eg4*2 + m;
      const float as = as_sh[e];
      const float a0 = av0_sh[e], a1 = av1_sh[e], a2 = av2_sh[e];
      float* base = out + (size_t)rcv_sh[e] * 256;
      #pragma unroll
      for (int j = 0; j < 4; j++){
        const int o = og4*4 + j;
        const float s2a = sbuf[e][o];
        const float s2b = sbuf[e][64 + o];
        atomicAdd(base + o, s2a * fast_sigmoid(s2a));
        const float g  = fast_sigmoid(s2b);
        const float tt = acc2T[j][m];
        atomicAdd(base + 64 + o*3 + 0, (tt*a0 + as*acc2U[0][j][m]) * INV_M2 * g);
        atomicAdd(base + 64 + o*3 + 1, (tt*a1 + as*acc2U[1][j][m]) * INV_M2 * g);
        atomicAdd(base + 64 + o*3 + 2, (tt*a2 + as*acc2U[2][j][m]) * INV_M2 * g);
      }
    }
  }
}

// =====================================================================
// NODE KERNEL (round-2 structure, unchanged): u0 (gated) -> u1 -> residual
// =====================================================================
template<int K, int ROWBASE>
__device__ __forceinline__ void gemm_s_n(float acc[4][2], const float* __restrict__ W,
                                         float (*A_T)[AP], int t){
  const int og = t & 31;
  const int eg = t >> 5;
  const float4* __restrict__ W4 = (const float4*)W;
  #pragma unroll 8
  for (int k = 0; k < K; k++){
    const float4 w = W4[k*32 + og];
    const float2 a = *(const float2*)(&A_T[ROWBASE + k][eg*2]);
    acc[0][0] = fmaf(w.x, a.x, acc[0][0]); acc[0][1] = fmaf(w.x, a.y, acc[0][1]);
    acc[1][0] = fmaf(w.y, a.x, acc[1][0]); acc[1][1] = fmaf(w.y, a.y, acc[1][1]);
    acc[2][0] = fmaf(w.z, a.x, acc[2][0]); acc[2][1] = fmaf(w.z, a.y, acc[2][1]);
    acc[3][0] = fmaf(w.w, a.x, acc[3][0]); acc[3][1] = fmaf(w.w, a.y, acc[3][1]);
  }
}

template<int K, int ROWBASE>
__device__ __forceinline__ void gemm_t_n(float acc[4], const float* __restrict__ W,
                                         float (*A_T)[AP], int t){
  const int og = t & 15;
  const int eg = t >> 4;
  const float4* __restrict__ W4 = (const float4*)W;
  #pragma unroll 8
  for (int k = 0; k < K; k++){
    const float4 w = W4[k*16 + og];
    const float a = A_T[ROWBASE + k][eg];
    acc[0] = fmaf(w.x, a, acc[0]); acc[1] = fmaf(w.y, a, acc[1]);
    acc[2] = fmaf(w.z, a, acc[2]); acc[3] = fmaf(w.w, a, acc[3]);
  }
}

template<int K>
__device__ __forceinline__ void gemm_u_n(float acc[3][4], const float* __restrict__ W,
                                         float (*V_T)[VP], int t){
  const int og = t & 15;
  const int eg = t >> 4;
  const float4* __restrict__ W4 = (const float4*)W;
  #pragma unroll 4
  for (int k = 0; k < K; k++){
    const float4 w = W4[k*16 + og];
    const float a0 = V_T[k][eg], a1 = V_T[k][16+eg], a2 = V_T[k][32+eg];
    acc[0][0] = fmaf(w.x,a0,acc[0][0]); acc[0][1] = fmaf(w.y,a0,acc[0][1]);
    acc[0][2] = fmaf(w.z,a0,acc[0][2]); acc[0][3] = fmaf(w.w,a0,acc[0][3]);
    acc[1][0] = fmaf(w.x,a1,acc[1][0]); acc[1][1] = fmaf(w.y,a1,acc[1][1]);
    acc[1][2] = fmaf(w.z,a1,acc[1][2]); acc[1][3] = fmaf(w.w,a1,acc[1][3]);
    acc[2][0] = fmaf(w.x,a2,acc[2][0]); acc[2][1] = fmaf(w.y,a2,acc[2][1]);
    acc[2][2] = fmaf(w.z,a2,acc[2][2]); acc[2][3] = fmaf(w.w,a2,acc[2][3]);
  }
}

__global__ __launch_bounds__(256, 3) void node_kernel(
    const float* __restrict__ node_s, const float* __restrict__ node_v,
    const float* __restrict__ node_attr_s, const float* __restrict__ node_attr_v,
    const float* __restrict__ Wss0, const float* __restrict__ Wvs0,
    const float* __restrict__ Wsv0, const float* __restrict__ Wvv0,
    const float* __restrict__ b0,
    const float* __restrict__ Wss1, const float* __restrict__ Wvs1,
    const float* __restrict__ Wsv1, const float* __restrict__ Wvv1,
    const float* __restrict__ b1u,
    float* __restrict__ out)
{
  __shared__ float A_T[256][AP];
  __shared__ float V_T[128][VP];
  __shared__ float s_buf[TE][129];
  __shared__ float a_s_sh[TE];
  __shared__ float av_sh[TE][3];

  const int t = threadIdx.x;
  const int n0 = blockIdx.x * TE;

  if (t < TE) a_s_sh[t] = node_attr_s[n0 + t];
  if (t < TE*3) av_sh[t/3][t%3] = node_attr_v[n0*3 + t];
  {
    const int e = t >> 4, l = t & 15;
    const int n = n0 + e;
    float4 v4 = ((const float4*)(node_s + (size_t)n*64))[l];
    A_T[l*4+0][e] = v4.x; A_T[l*4+1][e] = v4.y;
    A_T[l*4+2][e] = v4.z; A_T[l*4+3][e] = v4.w;
    v4 = ((const float4*)(out + (size_t)n*256))[l];
    A_T[64+l*4+0][e] = v4.x; A_T[64+l*4+1][e] = v4.y;
    A_T[64+l*4+2][e] = v4.z; A_T[64+l*4+3][e] = v4.w;
    const float4* pvn = (const float4*)(node_v + (size_t)n*192);
    const float4* pva = (const float4*)(out + (size_t)n*256 + 64);
    #pragma unroll
    for (int q = 0; q < 3; q++){
      float4 w4 = pvn[l*3+q];
      int f = (l*3+q)*4;
      float vals[4] = {w4.x, w4.y, w4.z, w4.w};
      #pragma unroll
      for (int j = 0; j < 4; j++){
        int ff = f + j, vv = ff/3, ii = ff - vv*3;
        V_T[vv][ii*16 + e] = vals[j];
      }
      w4 = pva[l*3+q];
      float vals2[4] = {w4.x, w4.y, w4.z, w4.w};
      #pragma unroll
      for (int j = 0; j < 4; j++){
        int ff = f + j, vv = ff/3, ii = ff - vv*3;
        V_T[64 + vv][ii*16 + e] = vals2[j];
      }
    }
  }
  __syncthreads();
  {
    const int e = t >> 4, l = t & 15;
    const float a0 = av_sh[e][0], a1 = av_sh[e][1], a2 = av_sh[e][2];
    #pragma unroll
    for (int r = 0; r < 8; r++){
      int v = l*8 + r;
      float q = V_T[v][e]*a0 + V_T[v][16+e]*a1 + V_T[v][32+e]*a2;
      A_T[128 + v][e] = q * RSQRT3;
    }
  }
  __syncthreads();

  float acc_a[4][2] = {{0.f,0.f},{0.f,0.f},{0.f,0.f},{0.f,0.f}};
  float acc_b[4][2] = {{0.f,0.f},{0.f,0.f},{0.f,0.f},{0.f,0.f}};
  gemm_s_n<128, 0>(acc_a, Wss0, A_T, t);
  gemm_s_n<128, 128>(acc_b, Wvs0, A_T, t);
  {
    const int og = t & 31, eg = t >> 5;
    #pragma unroll
    for (int m = 0; m < 2; m++){
      const int e = eg*2 + m;
      const float as = a_s_sh[e];
      #pragma unroll
      for (int j = 0; j < 4; j++){
        const int o = og*4 + j;
        s_buf[e][o] = (as*acc_a[j][m] + acc_b[j][m]) * INV_U0 + b0[o];
      }
    }
  }
  float accT[4] = {0.f,0.f,0.f,0.f};
  gemm_t_n<128, 0>(accT, Wsv0, A_T, t);
  float accU[3][4] = {};
  gemm_u_n<128>(accU, Wvv0, V_T, t);
  __syncthreads();
  {
    const int og = t & 15, e = t >> 4;
    const float as = a_s_sh[e];
    const float a0 = av_sh[e][0], a1 = av_sh[e][1], a2 = av_sh[e][2];
    #pragma unroll
    for (int j = 0; j < 4; j++){
      const int o = og*4 + j;
      const float s1v = s_buf[e][o];
      const float hs = s1v * fast_sigmoid(s1v);
      const float g  = fast_sigmoid(s_buf[e][64+o]);
      const float tt = accT[j];
      const float hv0 = (tt*a0 + as*accU[0][j]) * INV_U0 * g;
      const float hv1 = (tt*a1 + as*accU[1][j]) * INV_U0 * g;
      const float hv2 = (tt*a2 + as*accU[2][j]) * INV_U0 * g;
      A_T[o][e] = hs;
      V_T[o][e] = hv0; V_T[o][16+e] = hv1; V_T[o][32+e] = hv2;
      A_T[64+o][e] = (hv0*a0 + hv1*a1 + hv2*a2) * RSQRT3;
    }
  }
  __syncthreads();

  float sa[4] = {0.f,0.f,0.f,0.f};
  float sb[4] = {0.f,0.f,0.f,0.f};
  gemm_t_n<64, 0>(sa, Wss1, A_T, t);
  gemm_t_n<64, 64>(sb, Wvs1, A_T, t);
  float accT2[4] = {0.f,0.f,0.f,0.f};
  gemm_t_n<64, 0>(accT2, Wsv1, A_T, t);
  float accU2[3][4] = {};
  gemm_u_n<64>(accU2, Wvv1, V_T, t);
  {
    const int og = t & 15, e = t >> 4;
    const int n = n0 + e;
    const float as = a_s_sh[e];
    const float a0 = av_sh[e][0], a1 = av_sh[e][1], a2 = av_sh[e][2];
    #pragma unroll
    for (int j = 0; j < 4; j++){
      const int o = og*4 + j;
      const float us = (as*sa[j] + sb[j]) * INV_U1 + b1u[o];
      out[(size_t)n*256 + o] = node_s[(size_t)n*64 + o] + us;
      const float tt = accT2[j];
      out[(size_t)n*256 + 64 + o*3 + 0] = node_v[(size_t)n*192 + o*3 + 0] + (tt*a0 + as*accU2[0][j]) * INV_U1;
      out[(size_t)n*256 + 64 + o*3 + 1] = node_v[(size_t)n*192 + o*3 + 1] + (tt*a1 + as*accU2[1][j]) * INV_U1;
      out[(size_t)n*256 + 64 + o*3 + 2] = node_v[(size_t)n*192 + o*3 + 2] + (tt*a2 + as*accU2[2][j]) * INV_U1;
    }
  }
}

extern "C" void kernel_launch(void* const* d_in, const int* in_sizes, int n_in,
                              void* d_out, int out_size, void* d_ws, size_t ws_size,
                              hipStream_t stream) {
  const float* node_s      = (const float*)d_in[0];
  const float* node_v      = (const float*)d_in[1];
  const float* node_attr_s = (const float*)d_in[2];
  const float* node_attr_v = (const float*)d_in[3];
  const float* edge_attr_s = (const float*)d_in[4];
  const float* edge_attr_v = (const float*)d_in[5];
  const float* add_feat    = (const float*)d_in[6];
  const float* m1_Wss = (const float*)d_in[7];
  const float* m1_Wvs = (const float*)d_in[8];
  const float* m1_Wsv = (const float*)d_in[9];
  const float* m1_Wvv = (const float*)d_in[10];
  const float* m1_b   = (const float*)d_in[11];
  const float* m2_Wss = (const float*)d_in[12];
  const float* m2_Wvs = (const float*)d_in[13];
  const float* m2_Wsv = (const float*)d_in[14];
  const float* m2_Wvv = (const float*)d_in[15];
  const float* m2_b   = (const float*)d_in[16];
  const float* u0_Wss = (const float*)d_in[17];
  const float* u0_Wvs = (const float*)d_in[18];
  const float* u0_Wsv = (const float*)d_in[19];
  const float* u0_Wvv = (const float*)d_in[20];
  const float* u0_b   = (const float*)d_in[21];
  const float* u1_Wss = (const float*)d_in[22];
  const float* u1_Wvs = (const float*)d_in[23];
  const float* u1_Wsv = (const float*)d_in[24];
  const float* u1_Wvv = (const float*)d_in[25];
  const float* u1_b   = (const float*)d_in[26];
  const int* senders   = (const int*)d_in[27];
  const int* receivers = (const int*)d_in[28];
  float* out = (float*)d_out;

  hipMemsetAsync(d_out, 0, (size_t)out_size * sizeof(float), stream);

  edge_kernel<<<NEDGES / ET, 512, 0, stream>>>(
      node_s, node_v, edge_attr_s, edge_attr_v, add_feat, senders, receivers,
      m1_Wss, m1_Wvs, m1_Wsv, m1_Wvv, m1_b,
      m2_Wss, m2_Wvs, m2_Wsv, m2_Wvv, m2_b, out);

  node_kernel<<<NNODES / TE, 256, 0, stream>>>(
      node_s, node_v, node_attr_s, node_attr_v,
      u0_Wss, u0_Wvs, u0_Wsv, u0_Wvv, u0_b,
      u1_Wss, u1_Wvs, u1_Wsv, u1_Wvv, u1_b, out);
}

// Round 4
// 4183.414 us; speedup vs baseline: 1.1811x; 1.0033x over previous
//
#include <hip/hip_runtime.h>

#define NNODES 50000
#define NEDGES 400000

// ---- node-kernel tile params ----
#define TE 16
#define AP 18
#define VP 50

// ---- edge-kernel params ----
#define ET 64      // edges per block
#define QW 68      // Q / msT row stride
#define SW 132     // sbuf row stride
#define VW 194     // V row stride

constexpr float RSQRT3 = 0.57735026918962576f;
constexpr float INV_M1 = 0.062257280630559f;   // 1/sqrt(130+128)
constexpr float INV_M2 = 0.088388347648318f;   // 1/sqrt(64+64)
constexpr float INV_U0 = 0.0625f;              // 1/sqrt(128+128)
constexpr float INV_U1 = 0.088388347648318f;   // 1/sqrt(64+64)

__device__ __forceinline__ float fast_sigmoid(float x){ return 1.0f / (1.0f + __expf(-x)); }

// =====================================================================
// CSR-build kernels
// =====================================================================
__global__ __launch_bounds__(256) void hist_kernel(const int* __restrict__ recv, int* __restrict__ cnt){
  const int e = blockIdx.x * 256 + threadIdx.x;
  if (e < NEDGES) atomicAdd(&cnt[recv[e]], 1);
}

__global__ __launch_bounds__(1024) void scan_kernel(const int* __restrict__ cnt, int* __restrict__ offs){
  __shared__ int ssum[1024];
  const int t = threadIdx.x;
  const int C = (NNODES + 1023) / 1024;   // 49
  const int base = t * C;
  int s = 0;
  for (int i = 0; i < C; i++){
    const int idx = base + i;
    if (idx < NNODES) s += cnt[idx];
  }
  ssum[t] = s;
  __syncthreads();
  for (int off = 1; off < 1024; off <<= 1){
    int v = (t >= off) ? ssum[t - off] : 0;
    __syncthreads();
    ssum[t] += v;
    __syncthreads();
  }
  int run = (t == 0) ? 0 : ssum[t - 1];
  for (int i = 0; i < C; i++){
    const int idx = base + i;
    if (idx < NNODES){ offs[idx] = run; run += cnt[idx]; }
  }
  if (t == 1023) offs[NNODES] = run;   // == NEDGES
}

__global__ __launch_bounds__(256) void place_kernel(const int* __restrict__ recv,
                                                    const int* __restrict__ offs,
                                                    int* __restrict__ cur,
                                                    int* __restrict__ elist){
  const int e = blockIdx.x * 256 + threadIdx.x;
  if (e < NEDGES){
    const int r = recv[e];
    const int p = atomicAdd(&cur[r], 1);
    elist[offs[r] + p] = e;
  }
}

// =====================================================================
// gather kernel: out[n] = sum of msg[e] over CSR list (coalesced float4)
// =====================================================================
__global__ __launch_bounds__(64) void gather_kernel(const float* __restrict__ msg,
                                                    const int* __restrict__ elist,
                                                    const int* __restrict__ offs,
                                                    float* __restrict__ out){
  const int n = blockIdx.x;
  const int t = threadIdx.x;
  const int b = offs[n], e2 = offs[n + 1];
  float4 acc = {0.f, 0.f, 0.f, 0.f};
  float4 acc2 = {0.f, 0.f, 0.f, 0.f};
  int j = b;
  for (; j + 1 < e2; j += 2){
    const float4 v1 = ((const float4*)(msg + (size_t)elist[j] * 256))[t];
    const float4 v2 = ((const float4*)(msg + (size_t)elist[j+1] * 256))[t];
    acc.x += v1.x; acc.y += v1.y; acc.z += v1.z; acc.w += v1.w;
    acc2.x += v2.x; acc2.y += v2.y; acc2.z += v2.z; acc2.w += v2.w;
  }
  if (j < e2){
    const float4 v1 = ((const float4*)(msg + (size_t)elist[j] * 256))[t];
    acc.x += v1.x; acc.y += v1.y; acc.z += v1.z; acc.w += v1.w;
  }
  acc.x += acc2.x; acc.y += acc2.y; acc.z += acc2.z; acc.w += acc2.w;
  ((float4*)(out + (size_t)n * 256))[t] = acc;
}

// =====================================================================
// EDGE KERNEL: 64 edges / 512 threads. m1 (gated) -> m2 (gated) -> msg write
// (MSG=true) or atomic aggregate (MSG=false fallback).
// =====================================================================
template<bool MSG>
__global__ __launch_bounds__(512, 2) void edge_kernel(
    const float* __restrict__ node_s, const float* __restrict__ node_v,
    const float* __restrict__ edge_attr_s, const float* __restrict__ edge_attr_v,
    const float* __restrict__ add_feat,
    const int* __restrict__ senders, const int* __restrict__ receivers,
    const float* __restrict__ Wss1, const float* __restrict__ Wvs1,
    const float* __restrict__ Wsv1, const float* __restrict__ Wvv1,
    const float* __restrict__ b1,
    const float* __restrict__ Wss2, const float* __restrict__ Wvs2,
    const float* __restrict__ Wsv2, const float* __restrict__ Wvv2,
    const float* __restrict__ b2,
    float* __restrict__ dst)   // MSG: msg buffer [E][256]; else: out aggregates
{
  __shared__ __align__(16) float Qreg[128][QW];
  __shared__ __align__(16) float sbuf[ET][SW];
  __shared__ __align__(16) float VC[ET][VW];
  __shared__ __align__(16) float af_sh[2][QW];
  __shared__ float as_sh[ET], av0_sh[ET], av1_sh[ET], av2_sh[ET];
  __shared__ int snd_sh[ET], rcv_sh[ET];

  const int t   = threadIdx.x;
  const int e0  = blockIdx.x * ET;
  const int og5 = t & 31, eg5 = t >> 5;
  const int og4 = t & 15, eg4 = t >> 4;

  if (t < ET){
    as_sh[t]  = edge_attr_s[e0 + t];
    snd_sh[t] = senders[e0 + t];
    rcv_sh[t] = receivers[e0 + t];
  } else if (t < 2*ET){
    const int e = t - ET;
    av0_sh[e] = edge_attr_v[(size_t)(e0+e)*3 + 0];
    av1_sh[e] = edge_attr_v[(size_t)(e0+e)*3 + 1];
    av2_sh[e] = edge_attr_v[(size_t)(e0+e)*3 + 2];
  } else if (t < 2*ET + 2*ET){
    const int x = t - 2*ET, e = x >> 1, d = x & 1;
    af_sh[d][e] = add_feat[(size_t)(e0+e)*2 + d];
  }
  __syncthreads();

  // ================= phase 1: V-tiles -> gemm_u(Wvv1) + build Q =================
  float accU[3][4][2] = {};
  for (int kt = 0; kt < 4; kt++){
    {
      const int e = t >> 3, q = t & 7;
      const int n = (kt < 2) ? snd_sh[e] : rcv_sh[e];
      const float4* src = (const float4*)(node_v + (size_t)n*192) + (kt & 1)*24 + q*3;
      float4 f0 = src[0], f1 = src[1], f2 = src[2];
      float f[12] = {f0.x,f0.y,f0.z,f0.w, f1.x,f1.y,f1.z,f1.w, f2.x,f2.y,f2.z,f2.w};
      const float a0 = av0_sh[e], a1 = av1_sh[e], a2 = av2_sh[e];
      #pragma unroll
      for (int d = 0; d < 4; d++){
        const int r = q*4 + d;
        VC[r][0*64 + e] = f[d*3+0];
        VC[r][1*64 + e] = f[d*3+1];
        VC[r][2*64 + e] = f[d*3+2];
        Qreg[kt*32 + r][e] = (f[d*3]*a0 + f[d*3+1]*a1 + f[d*3+2]*a2) * RSQRT3;
      }
    }
    __syncthreads();
    const float4* W4 = (const float4*)Wvv1 + (size_t)(kt*32)*16 + og4;
    #pragma unroll 4
    for (int r = 0; r < 32; r++){
      const float4 wv = W4[(size_t)r*16];
      const float w[4] = {wv.x, wv.y, wv.z, wv.w};
      const float2 a0 = *(const float2*)&VC[r][0*64 + eg4*2];
      const float2 a1 = *(const float2*)&VC[r][1*64 + eg4*2];
      const float2 a2 = *(const float2*)&VC[r][2*64 + eg4*2];
      const float av0a[2] = {a0.x, a0.y}, av1a[2] = {a1.x, a1.y}, av2a[2] = {a2.x, a2.y};
      #pragma unroll
      for (int j = 0; j < 4; j++){
        #pragma unroll
        for (int m = 0; m < 2; m++){
          accU[0][j][m] = fmaf(w[j], av0a[m], accU[0][j][m]);
          accU[1][j][m] = fmaf(w[j], av1a[m], accU[1][j][m]);
          accU[2][j][m] = fmaf(w[j], av2a[m], accU[2][j][m]);
        }
      }
    }
    __syncthreads();
  }

  // ================= phase 2: xs-tiles -> gemm_s(Wss1) + gemm_t(Wsv1) =================
  float accS[4][4] = {};
  float accT[4][2] = {};
  float (*A2)[QW] = (float(*)[QW])VC;
  for (int kt = 0; kt < 4; kt++){
    {
      const int e = t >> 3, q = t & 7;
      const int n = (kt < 2) ? snd_sh[e] : rcv_sh[e];
      const float4 f = ((const float4*)(node_s + (size_t)n*64))[(kt & 1)*8 + q];
      A2[q*4+0][e] = f.x; A2[q*4+1][e] = f.y; A2[q*4+2][e] = f.z; A2[q*4+3][e] = f.w;
    }
    __syncthreads();
    const float4* Wa = (const float4*)Wss1 + (size_t)(kt*32)*32 + og5;
    const float4* Wb = (const float4*)Wsv1 + (size_t)(kt*32)*16 + og4;
    #pragma unroll 4
    for (int r = 0; r < 32; r++){
      const float4 wav = Wa[(size_t)r*32];
      const float wa[4] = {wav.x, wav.y, wav.z, wav.w};
      const float4 a4 = *(const float4*)&A2[r][eg5*4];
      const float aa[4] = {a4.x, a4.y, a4.z, a4.w};
      #pragma unroll
      for (int j = 0; j < 4; j++)
        #pragma unroll
        for (int m = 0; m < 4; m++)
          accS[j][m] = fmaf(wa[j], aa[m], accS[j][m]);
      const float4 wbv = Wb[(size_t)r*16];
      const float wb[4] = {wbv.x, wbv.y, wbv.z, wbv.w};
      const float2 a2v = *(const float2*)&A2[r][eg4*2];
      const float ab[2] = {a2v.x, a2v.y};
      #pragma unroll
      for (int j = 0; j < 4; j++)
        #pragma unroll
        for (int m = 0; m < 2; m++)
          accT[j][m] = fmaf(wb[j], ab[m], accT[j][m]);
    }
    __syncthreads();
  }
  // tail rows 128..129 (add_feat)
  #pragma unroll
  for (int d = 0; d < 2; d++){
    const float4 wav = ((const float4*)Wss1)[(size_t)(128+d)*32 + og5];
    const float wa[4] = {wav.x, wav.y, wav.z, wav.w};
    const float4 a4 = *(const float4*)&af_sh[d][eg5*4];
    const float aa[4] = {a4.x, a4.y, a4.z, a4.w};
    #pragma unroll
    for (int j = 0; j < 4; j++)
      #pragma unroll
      for (int m = 0; m < 4; m++)
        accS[j][m] = fmaf(wa[j], aa[m], accS[j][m]);
    const float4 wbv = ((const float4*)Wsv1)[(size_t)(128+d)*16 + og4];
    const float wb[4] = {wbv.x, wbv.y, wbv.z, wbv.w};
    const float ab[2] = {af_sh[d][eg4*2], af_sh[d][eg4*2+1]};
    #pragma unroll
    for (int j = 0; j < 4; j++)
      #pragma unroll
      for (int m = 0; m < 2; m++)
        accT[j][m] = fmaf(wb[j], ab[m], accT[j][m]);
  }

  // ================= phase 3: gemm_s(Wvs1) over resident Q =================
  float accV[4][4] = {};
  {
    const float4* Wc = (const float4*)Wvs1 + og5;
    #pragma unroll 4
    for (int k = 0; k < 128; k++){
      const float4 wv = Wc[(size_t)k*32];
      const float w[4] = {wv.x, wv.y, wv.z, wv.w};
      const float4 a4 = *(const float4*)&Qreg[k][eg5*4];
      const float aa[4] = {a4.x, a4.y, a4.z, a4.w};
      #pragma unroll
      for (int j = 0; j < 4; j++)
        #pragma unroll
        for (int m = 0; m < 4; m++)
          accV[j][m] = fmaf(w[j], aa[m], accV[j][m]);
    }
  }
  {
    const float4 b1v = ((const float4*)b1)[og5];
    const float bb[4] = {b1v.x, b1v.y, b1v.z, b1v.w};
    #pragma unroll
    for (int m = 0; m < 4; m++){
      const int e = eg5*4 + m;
      const float as = as_sh[e];
      float4 s1;
      s1.x = (as*accS[0][m] + accV[0][m]) * INV_M1 + bb[0];
      s1.y = (as*accS[1][m] + accV[1][m]) * INV_M1 + bb[1];
      s1.z = (as*accS[2][m] + accV[2][m]) * INV_M1 + bb[2];
      s1.w = (as*accS[3][m] + accV[3][m]) * INV_M1 + bb[3];
      *(float4*)&sbuf[e][og5*4] = s1;
    }
  }
  __syncthreads();

  // ================= m1 epilogue =================
  {
    #pragma unroll
    for (int m = 0; m < 2; m++){
      const int e = eg4*2 + m;
      const float as = as_sh[e];
      const float a0 = av0_sh[e], a1 = av1_sh[e], a2 = av2_sh[e];
      #pragma unroll
      for (int j = 0; j < 4; j++){
        const int o = og4*4 + j;
        const float s1a = sbuf[e][o];
        const float s1b = sbuf[e][64 + o];
        const float ms = s1a * fast_sigmoid(s1a);
        const float g  = fast_sigmoid(s1b);
        const float tt = accT[j][m];
        const float mv0 = (tt*a0 + as*accU[0][j][m]) * INV_M1 * g;
        const float mv1 = (tt*a1 + as*accU[1][j][m]) * INV_M1 * g;
        const float mv2 = (tt*a2 + as*accU[2][j][m]) * INV_M1 * g;
        Qreg[o][e]      = ms;
        Qreg[64 + o][e] = (mv0*a0 + mv1*a1 + mv2*a2) * RSQRT3;
        VC[o][0*64 + e] = mv0; VC[o][1*64 + e] = mv1; VC[o][2*64 + e] = mv2;
      }
    }
  }
  __syncthreads();

  // ================= m2 =================
  float acc2S[4][4] = {};
  {
    const float4* Wd = (const float4*)Wss2 + og5;
    #pragma unroll 4
    for (int k = 0; k < 64; k++){
      const float4 wv = Wd[(size_t)k*32];
      const float w[4] = {wv.x, wv.y, wv.z, wv.w};
      const float4 a4 = *(const float4*)&Qreg[k][eg5*4];
      const float aa[4] = {a4.x, a4.y, a4.z, a4.w};
      #pragma unroll
      for (int j = 0; j < 4; j++)
        #pragma unroll
        for (int m = 0; m < 4; m++)
          acc2S[j][m] = fmaf(w[j], aa[m], acc2S[j][m]);
    }
  }
  float acc2V[4][4] = {};
  {
    const float4* We = (const float4*)Wvs2 + og5;
    #pragma unroll 4
    for (int k = 0; k < 64; k++){
      const float4 wv = We[(size_t)k*32];
      const float w[4] = {wv.x, wv.y, wv.z, wv.w};
      const float4 a4 = *(const float4*)&Qreg[64 + k][eg5*4];
      const float aa[4] = {a4.x, a4.y, a4.z, a4.w};
      #pragma unroll
      for (int j = 0; j < 4; j++)
        #pragma unroll
        for (int m = 0; m < 4; m++)
          acc2V[j][m] = fmaf(w[j], aa[m], acc2V[j][m]);
    }
  }
  {
    const float4 b2v = ((const float4*)b2)[og5];
    const float bb[4] = {b2v.x, b2v.y, b2v.z, b2v.w};
    #pragma unroll
    for (int m = 0; m < 4; m++){
      const int e = eg5*4 + m;
      const float as = as_sh[e];
      float4 s2;
      s2.x = (as*acc2S[0][m] + acc2V[0][m]) * INV_M2 + bb[0];
      s2.y = (as*acc2S[1][m] + acc2V[1][m]) * INV_M2 + bb[1];
      s2.z = (as*acc2S[2][m] + acc2V[2][m]) * INV_M2 + bb[2];
      s2.w = (as*acc2S[3][m] + acc2V[3][m]) * INV_M2 + bb[3];
      *(float4*)&sbuf[e][og5*4] = s2;
    }
  }
  float acc2T[4][2] = {};
  {
    const float4* Wf = (const float4*)Wsv2 + og4;
    #pragma unroll 4
    for (int k = 0; k < 64; k++){
      const float4 wv = Wf[(size_t)k*16];
      const float w[4] = {wv.x, wv.y, wv.z, wv.w};
      const float2 a2v = *(const float2*)&Qreg[k][eg4*2];
      const float aa[2] = {a2v.x, a2v.y};
      #pragma unroll
      for (int j = 0; j < 4; j++)
        #pragma unroll
        for (int m = 0; m < 2; m++)
          acc2T[j][m] = fmaf(w[j], aa[m], acc2T[j][m]);
    }
  }
  float acc2U[3][4][2] = {};
  {
    const float4* Wg = (const float4*)Wvv2 + og4;
    #pragma unroll 4
    for (int k = 0; k < 64; k++){
      const float4 wv = Wg[(size_t)k*16];
      const float w[4] = {wv.x, wv.y, wv.z, wv.w};
      const float2 a0 = *(const float2*)&VC[k][0*64 + eg4*2];
      const float2 a1 = *(const float2*)&VC[k][1*64 + eg4*2];
      const float2 a2 = *(const float2*)&VC[k][2*64 + eg4*2];
      const float av0a[2] = {a0.x, a0.y}, av1a[2] = {a1.x, a1.y}, av2a[2] = {a2.x, a2.y};
      #pragma unroll
      for (int j = 0; j < 4; j++)
        #pragma unroll
        for (int m = 0; m < 2; m++){
          acc2U[0][j][m] = fmaf(w[j], av0a[m], acc2U[0][j][m]);
          acc2U[1][j][m] = fmaf(w[j], av1a[m], acc2U[1][j][m]);
          acc2U[2][j][m] = fmaf(w[j], av2a[m], acc2U[2][j][m]);
        }
    }
  }
  __syncthreads();

  // ================= final epilogue =================
  {
    #pragma unroll
    for (int m = 0; m < 2; m++){
      const int e = eg4*2 + m;
      const float as = as_sh[e];
      const float a0 = av0_sh[e], a1 = av1_sh[e], a2 = av2_sh[e];
      if (MSG){
        float* base = dst + (size_t)(e0 + e) * 256;
        float4 sv;
        float vv[12];
        #pragma unroll
        for (int j = 0; j < 4; j++){
          const int o = og4*4 + j;
          const float s2a = sbuf[e][o];
          const float s2b = sbuf[e][64 + o];
          ((float*)&sv)[j] = s2a * fast_sigmoid(s2a);
          const float g  = fast_sigmoid(s2b);
          const float tt = acc2T[j][m];
          vv[j*3 + 0] = (tt*a0 + as*acc2U[0][j][m]) * INV_M2 * g;
          vv[j*3 + 1] = (tt*a1 + as*acc2U[1][j][m]) * INV_M2 * g;
          vv[j*3 + 2] = (tt*a2 + as*acc2U[2][j][m]) * INV_M2 * g;
        }
        *(float4*)(base + og4*4) = sv;
        float4* vp = (float4*)(base + 64 + og4*12);
        vp[0] = make_float4(vv[0], vv[1], vv[2], vv[3]);
        vp[1] = make_float4(vv[4], vv[5], vv[6], vv[7]);
        vp[2] = make_float4(vv[8], vv[9], vv[10], vv[11]);
      } else {
        float* base = dst + (size_t)rcv_sh[e] * 256;
        #pragma unroll
        for (int j = 0; j < 4; j++){
          const int o = og4*4 + j;
          const float s2a = sbuf[e][o];
          const float s2b = sbuf[e][64 + o];
          atomicAdd(base + o, s2a * fast_sigmoid(s2a));
          const float g  = fast_sigmoid(s2b);
          const float tt = acc2T[j][m];
          atomicAdd(base + 64 + o*3 + 0, (tt*a0 + as*acc2U[0][j][m]) * INV_M2 * g);
          atomicAdd(base + 64 + o*3 + 1, (tt*a1 + as*acc2U[1][j][m]) * INV_M2 * g);
          atomicAdd(base + 64 + o*3 + 2, (tt*a2 + as*acc2U[2][j][m]) * INV_M2 * g);
        }
      }
    }
  }
}

// =====================================================================
// NODE KERNEL: u0 (gated) -> u1 -> residual
// =====================================================================
template<int K, int ROWBASE>
__device__ __forceinline__ void gemm_s_n(float acc[4][2], const float* __restrict__ W,
                                         float (*A_T)[AP], int t){
  const int og = t & 31;
  const int eg = t >> 5;
  const float4* __restrict__ W4 = (const float4*)W;
  #pragma unroll 8
  for (int k = 0; k < K; k++){
    const float4 w = W4[k*32 + og];
    const float2 a = *(const float2*)(&A_T[ROWBASE + k][eg*2]);
    acc[0][0] = fmaf(w.x, a.x, acc[0][0]); acc[0][1] = fmaf(w.x, a.y, acc[0][1]);
    acc[1][0] = fmaf(w.y, a.x, acc[1][0]); acc[1][1] = fmaf(w.y, a.y, acc[1][1]);
    acc[2][0] = fmaf(w.z, a.x, acc[2][0]); acc[2][1] = fmaf(w.z, a.y, acc[2][1]);
    acc[3][0] = fmaf(w.w, a.x, acc[3][0]); acc[3][1] = fmaf(w.w, a.y, acc[3][1]);
  }
}

template<int K, int ROWBASE>
__device__ __forceinline__ void gemm_t_n(float acc[4], const float* __restrict__ W,
                                         float (*A_T)[AP], int t){
  const int og = t & 15;
  const int eg = t >> 4;
  const float4* __restrict__ W4 = (const float4*)W;
  #pragma unroll 8
  for (int k = 0; k < K; k++){
    const float4 w = W4[k*16 + og];
    const float a = A_T[ROWBASE + k][eg];
    acc[0] = fmaf(w.x, a, acc[0]); acc[1] = fmaf(w.y, a, acc[1]);
    acc[2] = fmaf(w.z, a, acc[2]); acc[3] = fmaf(w.w, a, acc[3]);
  }
}

template<int K>
__device__ __forceinline__ void gemm_u_n(float acc[3][4], const float* __restrict__ W,
                                         float (*V_T)[VP], int t){
  const int og = t & 15;
  const int eg = t >> 4;
  const float4* __restrict__ W4 = (const float4*)W;
  #pragma unroll 4
  for (int k = 0; k < K; k++){
    const float4 w = W4[k*16 + og];
    const float a0 = V_T[k][eg], a1 = V_T[k][16+eg], a2 = V_T[k][32+eg];
    acc[0][0] = fmaf(w.x,a0,acc[0][0]); acc[0][1] = fmaf(w.y,a0,acc[0][1]);
    acc[0][2] = fmaf(w.z,a0,acc[0][2]); acc[0][3] = fmaf(w.w,a0,acc[0][3]);
    acc[1][0] = fmaf(w.x,a1,acc[1][0]); acc[1][1] = fmaf(w.y,a1,acc[1][1]);
    acc[1][2] = fmaf(w.z,a1,acc[1][2]); acc[1][3] = fmaf(w.w,a1,acc[1][3]);
    acc[2][0] = fmaf(w.x,a2,acc[2][0]); acc[2][1] = fmaf(w.y,a2,acc[2][1]);
    acc[2][2] = fmaf(w.z,a2,acc[2][2]); acc[2][3] = fmaf(w.w,a2,acc[2][3]);
  }
}

__global__ __launch_bounds__(256, 3) void node_kernel(
    const float* __restrict__ node_s, const float* __restrict__ node_v,
    const float* __restrict__ node_attr_s, const float* __restrict__ node_attr_v,
    const float* __restrict__ Wss0, const float* __restrict__ Wvs0,
    const float* __restrict__ Wsv0, const float* __restrict__ Wvv0,
    const float* __restrict__ b0,
    const float* __restrict__ Wss1, const float* __restrict__ Wvs1,
    const float* __restrict__ Wsv1, const float* __restrict__ Wvv1,
    const float* __restrict__ b1u,
    float* __restrict__ out)
{
  __shared__ float A_T[256][AP];
  __shared__ float V_T[128][VP];
  __shared__ float s_buf[TE][129];
  __shared__ float a_s_sh[TE];
  __shared__ float av_sh[TE][3];

  const int t = threadIdx.x;
  const int n0 = blockIdx.x * TE;

  if (t < TE) a_s_sh[t] = node_attr_s[n0 + t];
  if (t < TE*3) av_sh[t/3][t%3] = node_attr_v[n0*3 + t];
  {
    const int e = t >> 4, l = t & 15;
    const int n = n0 + e;
    float4 v4 = ((const float4*)(node_s + (size_t)n*64))[l];
    A_T[l*4+0][e] = v4.x; A_T[l*4+1][e] = v4.y;
    A_T[l*4+2][e] = v4.z; A_T[l*4+3][e] = v4.w;
    v4 = ((const float4*)(out + (size_t)n*256))[l];
    A_T[64+l*4+0][e] = v4.x; A_T[64+l*4+1][e] = v4.y;
    A_T[64+l*4+2][e] = v4.z; A_T[64+l*4+3][e] = v4.w;
    const float4* pvn = (const float4*)(node_v + (size_t)n*192);
    const float4* pva = (const float4*)(out + (size_t)n*256 + 64);
    #pragma unroll
    for (int q = 0; q < 3; q++){
      float4 w4 = pvn[l*3+q];
      int f = (l*3+q)*4;
      float vals[4] = {w4.x, w4.y, w4.z, w4.w};
      #pragma unroll
      for (int j = 0; j < 4; j++){
        int ff = f + j, vv = ff/3, ii = ff - vv*3;
        V_T[vv][ii*16 + e] = vals[j];
      }
      w4 = pva[l*3+q];
      float vals2[4] = {w4.x, w4.y, w4.z, w4.w};
      #pragma unroll
      for (int j = 0; j < 4; j++){
        int ff = f + j, vv = ff/3, ii = ff - vv*3;
        V_T[64 + vv][ii*16 + e] = vals2[j];
      }
    }
  }
  __syncthreads();
  {
    const int e = t >> 4, l = t & 15;
    const float a0 = av_sh[e][0], a1 = av_sh[e][1], a2 = av_sh[e][2];
    #pragma unroll
    for (int r = 0; r < 8; r++){
      int v = l*8 + r;
      float q = V_T[v][e]*a0 + V_T[v][16+e]*a1 + V_T[v][32+e]*a2;
      A_T[128 + v][e] = q * RSQRT3;
    }
  }
  __syncthreads();

  float acc_a[4][2] = {{0.f,0.f},{0.f,0.f},{0.f,0.f},{0.f,0.f}};
  float acc_b[4][2] = {{0.f,0.f},{0.f,0.f},{0.f,0.f},{0.f,0.f}};
  gemm_s_n<128, 0>(acc_a, Wss0, A_T, t);
  gemm_s_n<128, 128>(acc_b, Wvs0, A_T, t);
  {
    const int og = t & 31, eg = t >> 5;
    #pragma unroll
    for (int m = 0; m < 2; m++){
      const int e = eg*2 + m;
      const float as = a_s_sh[e];
      #pragma unroll
      for (int j = 0; j < 4; j++){
        const int o = og*4 + j;
        s_buf[e][o] = (as*acc_a[j][m] + acc_b[j][m]) * INV_U0 + b0[o];
      }
    }
  }
  float accT[4] = {0.f,0.f,0.f,0.f};
  gemm_t_n<128, 0>(accT, Wsv0, A_T, t);
  float accU[3][4] = {};
  gemm_u_n<128>(accU, Wvv0, V_T, t);
  __syncthreads();
  {
    const int og = t & 15, e = t >> 4;
    const float as = a_s_sh[e];
    const float a0 = av_sh[e][0], a1 = av_sh[e][1], a2 = av_sh[e][2];
    #pragma unroll
    for (int j = 0; j < 4; j++){
      const int o = og*4 + j;
      const float s1v = s_buf[e][o];
      const float hs = s1v * fast_sigmoid(s1v);
      const float g  = fast_sigmoid(s_buf[e][64+o]);
      const float tt = accT[j];
      const float hv0 = (tt*a0 + as*accU[0][j]) * INV_U0 * g;
      const float hv1 = (tt*a1 + as*accU[1][j]) * INV_U0 * g;
      const float hv2 = (tt*a2 + as*accU[2][j]) * INV_U0 * g;
      A_T[o][e] = hs;
      V_T[o][e] = hv0; V_T[o][16+e] = hv1; V_T[o][32+e] = hv2;
      A_T[64+o][e] = (hv0*a0 + hv1*a1 + hv2*a2) * RSQRT3;
    }
  }
  __syncthreads();

  float sa[4] = {0.f,0.f,0.f,0.f};
  float sb[4] = {0.f,0.f,0.f,0.f};
  gemm_t_n<64, 0>(sa, Wss1, A_T, t);
  gemm_t_n<64, 64>(sb, Wvs1, A_T, t);
  float accT2[4] = {0.f,0.f,0.f,0.f};
  gemm_t_n<64, 0>(accT2, Wsv1, A_T, t);
  float accU2[3][4] = {};
  gemm_u_n<64>(accU2, Wvv1, V_T, t);
  {
    const int og = t & 15, e = t >> 4;
    const int n = n0 + e;
    const float as = a_s_sh[e];
    const float a0 = av_sh[e][0], a1 = av_sh[e][1], a2 = av_sh[e][2];
    #pragma unroll
    for (int j = 0; j < 4; j++){
      const int o = og*4 + j;
      const float us = (as*sa[j] + sb[j]) * INV_U1 + b1u[o];
      out[(size_t)n*256 + o] = node_s[(size_t)n*64 + o] + us;
      const float tt = accT2[j];
      out[(size_t)n*256 + 64 + o*3 + 0] = node_v[(size_t)n*192 + o*3 + 0] + (tt*a0 + as*accU2[0][j]) * INV_U1;
      out[(size_t)n*256 + 64 + o*3 + 1] = node_v[(size_t)n*192 + o*3 + 1] + (tt*a1 + as*accU2[1][j]) * INV_U1;
      out[(size_t)n*256 + 64 + o*3 + 2] = node_v[(size_t)n*192 + o*3 + 2] + (tt*a2 + as*accU2[2][j]) * INV_U1;
    }
  }
}

extern "C" void kernel_launch(void* const* d_in, const int* in_sizes, int n_in,
                              void* d_out, int out_size, void* d_ws, size_t ws_size,
                              hipStream_t stream) {
  const float* node_s      = (const float*)d_in[0];
  const float* node_v      = (const float*)d_in[1];
  const float* node_attr_s = (const float*)d_in[2];
  const float* node_attr_v = (const float*)d_in[3];
  const float* edge_attr_s = (const float*)d_in[4];
  const float* edge_attr_v = (const float*)d_in[5];
  const float* add_feat    = (const float*)d_in[6];
  const float* m1_Wss = (const float*)d_in[7];
  const float* m1_Wvs = (const float*)d_in[8];
  const float* m1_Wsv = (const float*)d_in[9];
  const float* m1_Wvv = (const float*)d_in[10];
  const float* m1_b   = (const float*)d_in[11];
  const float* m2_Wss = (const float*)d_in[12];
  const float* m2_Wvs = (const float*)d_in[13];
  const float* m2_Wsv = (const float*)d_in[14];
  const float* m2_Wvv = (const float*)d_in[15];
  const float* m2_b   = (const float*)d_in[16];
  const float* u0_Wss = (const float*)d_in[17];
  const float* u0_Wvs = (const float*)d_in[18];
  const float* u0_Wsv = (const float*)d_in[19];
  const float* u0_Wvv = (const float*)d_in[20];
  const float* u0_b   = (const float*)d_in[21];
  const float* u1_Wss = (const float*)d_in[22];
  const float* u1_Wvs = (const float*)d_in[23];
  const float* u1_Wsv = (const float*)d_in[24];
  const float* u1_Wvv = (const float*)d_in[25];
  const float* u1_b   = (const float*)d_in[26];
  const int* senders   = (const int*)d_in[27];
  const int* receivers = (const int*)d_in[28];
  float* out = (float*)d_out;

  // workspace layout for the CSR path
  const size_t MSG_BYTES   = (size_t)NEDGES * 256 * sizeof(float);       // 409.6 MB
  const size_t ELIST_BYTES = (size_t)NEDGES * sizeof(int);
  const size_t OFFS_BYTES  = (size_t)(NNODES + 1) * sizeof(int);
  const size_t CUR_BYTES   = (size_t)NNODES * sizeof(int);
  const size_t NEED = MSG_BYTES + ELIST_BYTES + OFFS_BYTES + CUR_BYTES;

  if (ws_size >= NEED){
    char* w = (char*)d_ws;
    float* msg    = (float*)w;
    int*   elist  = (int*)(w + MSG_BYTES);
    int*   offs   = (int*)(w + MSG_BYTES + ELIST_BYTES);
    int*   cnt    = (int*)(w + MSG_BYTES + ELIST_BYTES + OFFS_BYTES);  // counts, then cursors

    hipMemsetAsync(cnt, 0, CUR_BYTES, stream);
    hist_kernel<<<(NEDGES + 255) / 256, 256, 0, stream>>>(receivers, cnt);
    scan_kernel<<<1, 1024, 0, stream>>>(cnt, offs);
    hipMemsetAsync(cnt, 0, CUR_BYTES, stream);
    place_kernel<<<(NEDGES + 255) / 256, 256, 0, stream>>>(receivers, offs, cnt, elist);

    edge_kernel<true><<<NEDGES / ET, 512, 0, stream>>>(
        node_s, node_v, edge_attr_s, edge_attr_v, add_feat, senders, receivers,
        m1_Wss, m1_Wvs, m1_Wsv, m1_Wvv, m1_b,
        m2_Wss, m2_Wvs, m2_Wsv, m2_Wvv, m2_b, msg);

    gather_kernel<<<NNODES, 64, 0, stream>>>(msg, elist, offs, out);
  } else {
    // fallback: atomic aggregation directly into out
    hipMemsetAsync(d_out, 0, (size_t)out_size * sizeof(float), stream);
    edge_kernel<false><<<NEDGES / ET, 512, 0, stream>>>(
        node_s, node_v, edge_attr_s, edge_attr_v, add_feat, senders, receivers,
        m1_Wss, m1_Wvs, m1_Wsv, m1_Wvv, m1_b,
        m2_Wss, m2_Wvs, m2_Wsv, m2_Wvv, m2_b, out);
  }

  node_kernel<<<NNODES / TE, 256, 0, stream>>>(
      node_s, node_v, node_attr_s, node_attr_v,
      u0_Wss, u0_Wvs, u0_Wsv, u0_Wvv, u0_b,
      u1_Wss, u1_Wvs, u1_Wsv, u1_Wvv, u1_b, out);
}

// Round 5
// 2406.837 us; speedup vs baseline: 2.0529x; 1.7381x over previous
//
#include <hip/hip_runtime.h>

#define NNODES 50000
#define NEDGES 400000

// ---- node-kernel tile params ----
#define TE 16
#define AP 18
#define VP 50

// ---- edge-kernel params ----
#define ET 64      // edges per block
#define QW 68      // Q / msT row stride
#define SW 132     // sbuf row stride
#define VW 194     // V row stride
#define MW 260     // LDS message row stride (float4-aligned)

// shared pool layout (floats)
#define OFF_Q   0
#define OFF_VC  8704            // 128*68
#define OFF_SB  21120           // + 64*194
#define POOLSZ  29568           // + 64*132

constexpr float RSQRT3 = 0.57735026918962576f;
constexpr float INV_M1 = 0.062257280630559f;   // 1/sqrt(130+128)
constexpr float INV_M2 = 0.088388347648318f;   // 1/sqrt(64+64)
constexpr float INV_U0 = 0.0625f;              // 1/sqrt(128+128)
constexpr float INV_U1 = 0.088388347648318f;   // 1/sqrt(64+64)

__device__ __forceinline__ float fast_sigmoid(float x){ return 1.0f / (1.0f + __expf(-x)); }

// =====================================================================
// CSR-build kernels (ws cost: ~2 MB)
// =====================================================================
__global__ __launch_bounds__(256) void hist_kernel(const int* __restrict__ recv, int* __restrict__ cnt){
  const int e = blockIdx.x * 256 + threadIdx.x;
  if (e < NEDGES) atomicAdd(&cnt[recv[e]], 1);
}

__global__ __launch_bounds__(1024) void scan_kernel(const int* __restrict__ cnt, int* __restrict__ offs){
  __shared__ int ssum[1024];
  const int t = threadIdx.x;
  const int C = (NNODES + 1023) / 1024;   // 49
  const int base = t * C;
  int s = 0;
  for (int i = 0; i < C; i++){
    const int idx = base + i;
    if (idx < NNODES) s += cnt[idx];
  }
  ssum[t] = s;
  __syncthreads();
  for (int off = 1; off < 1024; off <<= 1){
    int v = (t >= off) ? ssum[t - off] : 0;
    __syncthreads();
    ssum[t] += v;
    __syncthreads();
  }
  int run = (t == 0) ? 0 : ssum[t - 1];
  for (int i = 0; i < C; i++){
    const int idx = base + i;
    if (idx < NNODES){ offs[idx] = run; run += cnt[idx]; }
  }
  if (t == 1023) offs[NNODES] = run;
}

__global__ __launch_bounds__(256) void place_kernel(const int* __restrict__ recv,
                                                    const int* __restrict__ offs,
                                                    int* __restrict__ cur,
                                                    int* __restrict__ elist){
  const int e = blockIdx.x * 256 + threadIdx.x;
  if (e < NEDGES){
    const int r = recv[e];
    const int p = atomicAdd(&cur[r], 1);
    elist[offs[r] + p] = e;
  }
}

// =====================================================================
// EDGE KERNEL: 64 edges / 512 threads. m1 (gated) -> m2 (gated) ->
// MODE 1: receiver-sorted edges, LDS run-length combine, mostly plain stores
// MODE 0: direct atomic scatter fallback
// =====================================================================
template<int MODE>
__global__ __launch_bounds__(512, 2) void edge_kernel(
    const float* __restrict__ node_s, const float* __restrict__ node_v,
    const float* __restrict__ edge_attr_s, const float* __restrict__ edge_attr_v,
    const float* __restrict__ add_feat,
    const int* __restrict__ senders, const int* __restrict__ receivers,
    const int* __restrict__ elist,
    const float* __restrict__ Wss1, const float* __restrict__ Wvs1,
    const float* __restrict__ Wsv1, const float* __restrict__ Wvv1,
    const float* __restrict__ b1,
    const float* __restrict__ Wss2, const float* __restrict__ Wvs2,
    const float* __restrict__ Wsv2, const float* __restrict__ Wvv2,
    const float* __restrict__ b2,
    float* __restrict__ out)
{
  __shared__ __align__(16) float pool[POOLSZ];
  __shared__ __align__(16) float af_sh[2][QW];
  __shared__ float as_sh[ET], av0_sh[ET], av1_sh[ET], av2_sh[ET];
  __shared__ int snd_sh[ET], rcv_sh[ET], eid_sh[ET];

  float (*Qreg)[QW] = (float(*)[QW])(pool + OFF_Q);
  float (*VC)[VW]   = (float(*)[VW])(pool + OFF_VC);
  float (*sbuf)[SW] = (float(*)[SW])(pool + OFF_SB);
  float (*A2)[QW]   = (float(*)[QW])(pool + OFF_VC);   // phase-2 view of VC
  float* msgL = pool;                                   // epilogue overlay, stride MW

  const int t   = threadIdx.x;
  const int e0  = blockIdx.x * ET;
  const int og5 = t & 31, eg5 = t >> 5;
  const int og4 = t & 15, eg4 = t >> 4;

  if (t < ET) eid_sh[t] = MODE ? elist[e0 + t] : (e0 + t);
  __syncthreads();

  if (t < ET){
    const int eid = eid_sh[t];
    as_sh[t]  = edge_attr_s[eid];
    snd_sh[t] = senders[eid];
    rcv_sh[t] = receivers[eid];
  } else if (t < 2*ET){
    const int e = t - ET;
    const int eid = eid_sh[e];
    av0_sh[e] = edge_attr_v[(size_t)eid*3 + 0];
    av1_sh[e] = edge_attr_v[(size_t)eid*3 + 1];
    av2_sh[e] = edge_attr_v[(size_t)eid*3 + 2];
  } else if (t < 4*ET){
    const int x = t - 2*ET, e = x >> 1, d = x & 1;
    af_sh[d][e] = add_feat[(size_t)eid_sh[e]*2 + d];
  }
  __syncthreads();

  // ================= phase 1: V-tiles -> gemm_u(Wvv1) + build Q =================
  float accU[3][4][2] = {};
  for (int kt = 0; kt < 4; kt++){
    {
      const int e = t >> 3, q = t & 7;
      const int n = (kt < 2) ? snd_sh[e] : rcv_sh[e];
      const float4* src = (const float4*)(node_v + (size_t)n*192) + (kt & 1)*24 + q*3;
      float4 f0 = src[0], f1 = src[1], f2 = src[2];
      float f[12] = {f0.x,f0.y,f0.z,f0.w, f1.x,f1.y,f1.z,f1.w, f2.x,f2.y,f2.z,f2.w};
      const float a0 = av0_sh[e], a1 = av1_sh[e], a2 = av2_sh[e];
      #pragma unroll
      for (int d = 0; d < 4; d++){
        const int r = q*4 + d;
        VC[r][0*64 + e] = f[d*3+0];
        VC[r][1*64 + e] = f[d*3+1];
        VC[r][2*64 + e] = f[d*3+2];
        Qreg[kt*32 + r][e] = (f[d*3]*a0 + f[d*3+1]*a1 + f[d*3+2]*a2) * RSQRT3;
      }
    }
    __syncthreads();
    const float4* W4 = (const float4*)Wvv1 + (size_t)(kt*32)*16 + og4;
    #pragma unroll 4
    for (int r = 0; r < 32; r++){
      const float4 wv = W4[(size_t)r*16];
      const float w[4] = {wv.x, wv.y, wv.z, wv.w};
      const float2 a0 = *(const float2*)&VC[r][0*64 + eg4*2];
      const float2 a1 = *(const float2*)&VC[r][1*64 + eg4*2];
      const float2 a2 = *(const float2*)&VC[r][2*64 + eg4*2];
      const float av0a[2] = {a0.x, a0.y}, av1a[2] = {a1.x, a1.y}, av2a[2] = {a2.x, a2.y};
      #pragma unroll
      for (int j = 0; j < 4; j++){
        #pragma unroll
        for (int m = 0; m < 2; m++){
          accU[0][j][m] = fmaf(w[j], av0a[m], accU[0][j][m]);
          accU[1][j][m] = fmaf(w[j], av1a[m], accU[1][j][m]);
          accU[2][j][m] = fmaf(w[j], av2a[m], accU[2][j][m]);
        }
      }
    }
    __syncthreads();
  }

  // ================= phase 2: xs-tiles -> gemm_s(Wss1) + gemm_t(Wsv1) =================
  float accS[4][4] = {};
  float accT[4][2] = {};
  for (int kt = 0; kt < 4; kt++){
    {
      const int e = t >> 3, q = t & 7;
      const int n = (kt < 2) ? snd_sh[e] : rcv_sh[e];
      const float4 f = ((const float4*)(node_s + (size_t)n*64))[(kt & 1)*8 + q];
      A2[q*4+0][e] = f.x; A2[q*4+1][e] = f.y; A2[q*4+2][e] = f.z; A2[q*4+3][e] = f.w;
    }
    __syncthreads();
    const float4* Wa = (const float4*)Wss1 + (size_t)(kt*32)*32 + og5;
    const float4* Wb = (const float4*)Wsv1 + (size_t)(kt*32)*16 + og4;
    #pragma unroll 4
    for (int r = 0; r < 32; r++){
      const float4 wav = Wa[(size_t)r*32];
      const float wa[4] = {wav.x, wav.y, wav.z, wav.w};
      const float4 a4 = *(const float4*)&A2[r][eg5*4];
      const float aa[4] = {a4.x, a4.y, a4.z, a4.w};
      #pragma unroll
      for (int j = 0; j < 4; j++)
        #pragma unroll
        for (int m = 0; m < 4; m++)
          accS[j][m] = fmaf(wa[j], aa[m], accS[j][m]);
      const float4 wbv = Wb[(size_t)r*16];
      const float wb[4] = {wbv.x, wbv.y, wbv.z, wbv.w};
      const float2 a2v = *(const float2*)&A2[r][eg4*2];
      const float ab[2] = {a2v.x, a2v.y};
      #pragma unroll
      for (int j = 0; j < 4; j++)
        #pragma unroll
        for (int m = 0; m < 2; m++)
          accT[j][m] = fmaf(wb[j], ab[m], accT[j][m]);
    }
    __syncthreads();
  }
  // tail rows 128..129 (add_feat)
  #pragma unroll
  for (int d = 0; d < 2; d++){
    const float4 wav = ((const float4*)Wss1)[(size_t)(128+d)*32 + og5];
    const float wa[4] = {wav.x, wav.y, wav.z, wav.w};
    const float4 a4 = *(const float4*)&af_sh[d][eg5*4];
    const float aa[4] = {a4.x, a4.y, a4.z, a4.w};
    #pragma unroll
    for (int j = 0; j < 4; j++)
      #pragma unroll
      for (int m = 0; m < 4; m++)
        accS[j][m] = fmaf(wa[j], aa[m], accS[j][m]);
    const float4 wbv = ((const float4*)Wsv1)[(size_t)(128+d)*16 + og4];
    const float wb[4] = {wbv.x, wbv.y, wbv.z, wbv.w};
    const float ab[2] = {af_sh[d][eg4*2], af_sh[d][eg4*2+1]};
    #pragma unroll
    for (int j = 0; j < 4; j++)
      #pragma unroll
      for (int m = 0; m < 2; m++)
        accT[j][m] = fmaf(wb[j], ab[m], accT[j][m]);
  }

  // ================= phase 3: gemm_s(Wvs1) over resident Q =================
  float accV[4][4] = {};
  {
    const float4* Wc = (const float4*)Wvs1 + og5;
    #pragma unroll 4
    for (int k = 0; k < 128; k++){
      const float4 wv = Wc[(size_t)k*32];
      const float w[4] = {wv.x, wv.y, wv.z, wv.w};
      const float4 a4 = *(const float4*)&Qreg[k][eg5*4];
      const float aa[4] = {a4.x, a4.y, a4.z, a4.w};
      #pragma unroll
      for (int j = 0; j < 4; j++)
        #pragma unroll
        for (int m = 0; m < 4; m++)
          accV[j][m] = fmaf(w[j], aa[m], accV[j][m]);
    }
  }
  {
    const float4 b1v = ((const float4*)b1)[og5];
    const float bb[4] = {b1v.x, b1v.y, b1v.z, b1v.w};
    #pragma unroll
    for (int m = 0; m < 4; m++){
      const int e = eg5*4 + m;
      const float as = as_sh[e];
      float4 s1;
      s1.x = (as*accS[0][m] + accV[0][m]) * INV_M1 + bb[0];
      s1.y = (as*accS[1][m] + accV[1][m]) * INV_M1 + bb[1];
      s1.z = (as*accS[2][m] + accV[2][m]) * INV_M1 + bb[2];
      s1.w = (as*accS[3][m] + accV[3][m]) * INV_M1 + bb[3];
      *(float4*)&sbuf[e][og5*4] = s1;
    }
  }
  __syncthreads();

  // ================= m1 epilogue =================
  {
    #pragma unroll
    for (int m = 0; m < 2; m++){
      const int e = eg4*2 + m;
      const float as = as_sh[e];
      const float a0 = av0_sh[e], a1 = av1_sh[e], a2 = av2_sh[e];
      #pragma unroll
      for (int j = 0; j < 4; j++){
        const int o = og4*4 + j;
        const float s1a = sbuf[e][o];
        const float s1b = sbuf[e][64 + o];
        const float ms = s1a * fast_sigmoid(s1a);
        const float g  = fast_sigmoid(s1b);
        const float tt = accT[j][m];
        const float mv0 = (tt*a0 + as*accU[0][j][m]) * INV_M1 * g;
        const float mv1 = (tt*a1 + as*accU[1][j][m]) * INV_M1 * g;
        const float mv2 = (tt*a2 + as*accU[2][j][m]) * INV_M1 * g;
        Qreg[o][e]      = ms;
        Qreg[64 + o][e] = (mv0*a0 + mv1*a1 + mv2*a2) * RSQRT3;
        VC[o][0*64 + e] = mv0; VC[o][1*64 + e] = mv1; VC[o][2*64 + e] = mv2;
      }
    }
  }
  __syncthreads();

  // ================= m2 =================
  float acc2S[4][4] = {};
  {
    const float4* Wd = (const float4*)Wss2 + og5;
    #pragma unroll 4
    for (int k = 0; k < 64; k++){
      const float4 wv = Wd[(size_t)k*32];
      const float w[4] = {wv.x, wv.y, wv.z, wv.w};
      const float4 a4 = *(const float4*)&Qreg[k][eg5*4];
      const float aa[4] = {a4.x, a4.y, a4.z, a4.w};
      #pragma unroll
      for (int j = 0; j < 4; j++)
        #pragma unroll
        for (int m = 0; m < 4; m++)
          acc2S[j][m] = fmaf(w[j], aa[m], acc2S[j][m]);
    }
  }
  float acc2V[4][4] = {};
  {
    const float4* We = (const float4*)Wvs2 + og5;
    #pragma unroll 4
    for (int k = 0; k < 64; k++){
      const float4 wv = We[(size_t)k*32];
      const float w[4] = {wv.x, wv.y, wv.z, wv.w};
      const float4 a4 = *(const float4*)&Qreg[64 + k][eg5*4];
      const float aa[4] = {a4.x, a4.y, a4.z, a4.w};
      #pragma unroll
      for (int j = 0; j < 4; j++)
        #pragma unroll
        for (int m = 0; m < 4; m++)
          acc2V[j][m] = fmaf(w[j], aa[m], acc2V[j][m]);
    }
  }
  {
    const float4 b2v = ((const float4*)b2)[og5];
    const float bb[4] = {b2v.x, b2v.y, b2v.z, b2v.w};
    #pragma unroll
    for (int m = 0; m < 4; m++){
      const int e = eg5*4 + m;
      const float as = as_sh[e];
      float4 s2;
      s2.x = (as*acc2S[0][m] + acc2V[0][m]) * INV_M2 + bb[0];
      s2.y = (as*acc2S[1][m] + acc2V[1][m]) * INV_M2 + bb[1];
      s2.z = (as*acc2S[2][m] + acc2V[2][m]) * INV_M2 + bb[2];
      s2.w = (as*acc2S[3][m] + acc2V[3][m]) * INV_M2 + bb[3];
      *(float4*)&sbuf[e][og5*4] = s2;
    }
  }
  float acc2T[4][2] = {};
  {
    const float4* Wf = (const float4*)Wsv2 + og4;
    #pragma unroll 4
    for (int k = 0; k < 64; k++){
      const float4 wv = Wf[(size_t)k*16];
      const float w[4] = {wv.x, wv.y, wv.z, wv.w};
      const float2 a2v = *(const float2*)&Qreg[k][eg4*2];
      const float aa[2] = {a2v.x, a2v.y};
      #pragma unroll
      for (int j = 0; j < 4; j++)
        #pragma unroll
        for (int m = 0; m < 2; m++)
          acc2T[j][m] = fmaf(w[j], aa[m], acc2T[j][m]);
    }
  }
  float acc2U[3][4][2] = {};
  {
    const float4* Wg = (const float4*)Wvv2 + og4;
    #pragma unroll 4
    for (int k = 0; k < 64; k++){
      const float4 wv = Wg[(size_t)k*16];
      const float w[4] = {wv.x, wv.y, wv.z, wv.w};
      const float2 a0 = *(const float2*)&VC[k][0*64 + eg4*2];
      const float2 a1 = *(const float2*)&VC[k][1*64 + eg4*2];
      const float2 a2 = *(const float2*)&VC[k][2*64 + eg4*2];
      const float av0a[2] = {a0.x, a0.y}, av1a[2] = {a1.x, a1.y}, av2a[2] = {a2.x, a2.y};
      #pragma unroll
      for (int j = 0; j < 4; j++)
        #pragma unroll
        for (int m = 0; m < 2; m++){
          acc2U[0][j][m] = fmaf(w[j], av0a[m], acc2U[0][j][m]);
          acc2U[1][j][m] = fmaf(w[j], av1a[m], acc2U[1][j][m]);
          acc2U[2][j][m] = fmaf(w[j], av2a[m], acc2U[2][j][m]);
        }
    }
  }
  __syncthreads();   // Qreg/VC now dead -> msgL overlay is safe (sbuf still live)

  // ================= final epilogue =================
  if (MODE == 1){
    // write per-edge 256-float messages into LDS (overlay on Qreg+VC)
    #pragma unroll
    for (int m = 0; m < 2; m++){
      const int e = eg4*2 + m;
      const float as = as_sh[e];
      const float a0 = av0_sh[e], a1 = av1_sh[e], a2 = av2_sh[e];
      float* base = msgL + e*MW;
      float4 sv;
      float vv[12];
      #pragma unroll
      for (int j = 0; j < 4; j++){
        const int o = og4*4 + j;
        const float s2a = sbuf[e][o];
        const float s2b = sbuf[e][64 + o];
        ((float*)&sv)[j] = s2a * fast_sigmoid(s2a);
        const float g  = fast_sigmoid(s2b);
        const float tt = acc2T[j][m];
        vv[j*3 + 0] = (tt*a0 + as*acc2U[0][j][m]) * INV_M2 * g;
        vv[j*3 + 1] = (tt*a1 + as*acc2U[1][j][m]) * INV_M2 * g;
        vv[j*3 + 2] = (tt*a2 + as*acc2U[2][j][m]) * INV_M2 * g;
      }
      *(float4*)(base + og4*4) = sv;
      float4* vp = (float4*)(base + 64 + og4*12);
      vp[0] = make_float4(vv[0], vv[1], vv[2], vv[3]);
      vp[1] = make_float4(vv[4], vv[5], vv[6], vv[7]);
      vp[2] = make_float4(vv[8], vv[9], vv[10], vv[11]);
    }
    __syncthreads();
    // run-length combine over sorted receivers; one thread per feature
    if (t < 256){
      const int f = t;
      float acc = 0.f;
      int seg_start = 0;
      for (int ee = 0; ee < ET; ee++){
        acc += msgL[ee*MW + f];
        const int r = rcv_sh[ee];
        const bool last = (ee == ET-1);
        if (last || rcv_sh[ee+1] != r){
          float* dst = out + (size_t)r * 256 + f;
          if (seg_start == 0 || last) atomicAdd(dst, acc);   // run touches block boundary
          else *dst = acc;                                    // receiver fully owned by block
          acc = 0.f;
          seg_start = ee + 1;
        }
      }
    }
  } else {
    #pragma unroll
    for (int m = 0; m < 2; m++){
      const int e = eg4*2 + m;
      const float as = as_sh[e];
      const float a0 = av0_sh[e], a1 = av1_sh[e], a2 = av2_sh[e];
      float* base = out + (size_t)rcv_sh[e] * 256;
      #pragma unroll
      for (int j = 0; j < 4; j++){
        const int o = og4*4 + j;
        const float s2a = sbuf[e][o];
        const float s2b = sbuf[e][64 + o];
        atomicAdd(base + o, s2a * fast_sigmoid(s2a));
        const float g  = fast_sigmoid(s2b);
        const float tt = acc2T[j][m];
        atomicAdd(base + 64 + o*3 + 0, (tt*a0 + as*acc2U[0][j][m]) * INV_M2 * g);
        atomicAdd(base + 64 + o*3 + 1, (tt*a1 + as*acc2U[1][j][m]) * INV_M2 * g);
        atomicAdd(base + 64 + o*3 + 2, (tt*a2 + as*acc2U[2][j][m]) * INV_M2 * g);
      }
    }
  }
}

// =====================================================================
// NODE KERNEL: u0 (gated) -> u1 -> residual
// =====================================================================
template<int K, int ROWBASE>
__device__ __forceinline__ void gemm_s_n(float acc[4][2], const float* __restrict__ W,
                                         float (*A_T)[AP], int t){
  const int og = t & 31;
  const int eg = t >> 5;
  const float4* __restrict__ W4 = (const float4*)W;
  #pragma unroll 8
  for (int k = 0; k < K; k++){
    const float4 w = W4[k*32 + og];
    const float2 a = *(const float2*)(&A_T[ROWBASE + k][eg*2]);
    acc[0][0] = fmaf(w.x, a.x, acc[0][0]); acc[0][1] = fmaf(w.x, a.y, acc[0][1]);
    acc[1][0] = fmaf(w.y, a.x, acc[1][0]); acc[1][1] = fmaf(w.y, a.y, acc[1][1]);
    acc[2][0] = fmaf(w.z, a.x, acc[2][0]); acc[2][1] = fmaf(w.z, a.y, acc[2][1]);
    acc[3][0] = fmaf(w.w, a.x, acc[3][0]); acc[3][1] = fmaf(w.w, a.y, acc[3][1]);
  }
}

template<int K, int ROWBASE>
__device__ __forceinline__ void gemm_t_n(float acc[4], const float* __restrict__ W,
                                         float (*A_T)[AP], int t){
  const int og = t & 15;
  const int eg = t >> 4;
  const float4* __restrict__ W4 = (const float4*)W;
  #pragma unroll 8
  for (int k = 0; k < K; k++){
    const float4 w = W4[k*16 + og];
    const float a = A_T[ROWBASE + k][eg];
    acc[0] = fmaf(w.x, a, acc[0]); acc[1] = fmaf(w.y, a, acc[1]);
    acc[2] = fmaf(w.z, a, acc[2]); acc[3] = fmaf(w.w, a, acc[3]);
  }
}

template<int K>
__device__ __forceinline__ void gemm_u_n(float acc[3][4], const float* __restrict__ W,
                                         float (*V_T)[VP], int t){
  const int og = t & 15;
  const int eg = t >> 4;
  const float4* __restrict__ W4 = (const float4*)W;
  #pragma unroll 4
  for (int k = 0; k < K; k++){
    const float4 w = W4[k*16 + og];
    const float a0 = V_T[k][eg], a1 = V_T[k][16+eg], a2 = V_T[k][32+eg];
    acc[0][0] = fmaf(w.x,a0,acc[0][0]); acc[0][1] = fmaf(w.y,a0,acc[0][1]);
    acc[0][2] = fmaf(w.z,a0,acc[0][2]); acc[0][3] = fmaf(w.w,a0,acc[0][3]);
    acc[1][0] = fmaf(w.x,a1,acc[1][0]); acc[1][1] = fmaf(w.y,a1,acc[1][1]);
    acc[1][2] = fmaf(w.z,a1,acc[1][2]); acc[1][3] = fmaf(w.w,a1,acc[1][3]);
    acc[2][0] = fmaf(w.x,a2,acc[2][0]); acc[2][1] = fmaf(w.y,a2,acc[2][1]);
    acc[2][2] = fmaf(w.z,a2,acc[2][2]); acc[2][3] = fmaf(w.w,a2,acc[2][3]);
  }
}

__global__ __launch_bounds__(256, 3) void node_kernel(
    const float* __restrict__ node_s, const float* __restrict__ node_v,
    const float* __restrict__ node_attr_s, const float* __restrict__ node_attr_v,
    const float* __restrict__ Wss0, const float* __restrict__ Wvs0,
    const float* __restrict__ Wsv0, const float* __restrict__ Wvv0,
    const float* __restrict__ b0,
    const float* __restrict__ Wss1, const float* __restrict__ Wvs1,
    const float* __restrict__ Wsv1, const float* __restrict__ Wvv1,
    const float* __restrict__ b1u,
    float* __restrict__ out)
{
  __shared__ float A_T[256][AP];
  __shared__ float V_T[128][VP];
  __shared__ float s_buf[TE][129];
  __shared__ float a_s_sh[TE];
  __shared__ float av_sh[TE][3];

  const int t = threadIdx.x;
  const int n0 = blockIdx.x * TE;

  if (t < TE) a_s_sh[t] = node_attr_s[n0 + t];
  if (t < TE*3) av_sh[t/3][t%3] = node_attr_v[n0*3 + t];
  {
    const int e = t >> 4, l = t & 15;
    const int n = n0 + e;
    float4 v4 = ((const float4*)(node_s + (size_t)n*64))[l];
    A_T[l*4+0][e] = v4.x; A_T[l*4+1][e] = v4.y;
    A_T[l*4+2][e] = v4.z; A_T[l*4+3][e] = v4.w;
    v4 = ((const float4*)(out + (size_t)n*256))[l];
    A_T[64+l*4+0][e] = v4.x; A_T[64+l*4+1][e] = v4.y;
    A_T[64+l*4+2][e] = v4.z; A_T[64+l*4+3][e] = v4.w;
    const float4* pvn = (const float4*)(node_v + (size_t)n*192);
    const float4* pva = (const float4*)(out + (size_t)n*256 + 64);
    #pragma unroll
    for (int q = 0; q < 3; q++){
      float4 w4 = pvn[l*3+q];
      int f = (l*3+q)*4;
      float vals[4] = {w4.x, w4.y, w4.z, w4.w};
      #pragma unroll
      for (int j = 0; j < 4; j++){
        int ff = f + j, vv = ff/3, ii = ff - vv*3;
        V_T[vv][ii*16 + e] = vals[j];
      }
      w4 = pva[l*3+q];
      float vals2[4] = {w4.x, w4.y, w4.z, w4.w};
      #pragma unroll
      for (int j = 0; j < 4; j++){
        int ff = f + j, vv = ff/3, ii = ff - vv*3;
        V_T[64 + vv][ii*16 + e] = vals2[j];
      }
    }
  }
  __syncthreads();
  {
    const int e = t >> 4, l = t & 15;
    const float a0 = av_sh[e][0], a1 = av_sh[e][1], a2 = av_sh[e][2];
    #pragma unroll
    for (int r = 0; r < 8; r++){
      int v = l*8 + r;
      float q = V_T[v][e]*a0 + V_T[v][16+e]*a1 + V_T[v][32+e]*a2;
      A_T[128 + v][e] = q * RSQRT3;
    }
  }
  __syncthreads();

  float acc_a[4][2] = {{0.f,0.f},{0.f,0.f},{0.f,0.f},{0.f,0.f}};
  float acc_b[4][2] = {{0.f,0.f},{0.f,0.f},{0.f,0.f},{0.f,0.f}};
  gemm_s_n<128, 0>(acc_a, Wss0, A_T, t);
  gemm_s_n<128, 128>(acc_b, Wvs0, A_T, t);
  {
    const int og = t & 31, eg = t >> 5;
    #pragma unroll
    for (int m = 0; m < 2; m++){
      const int e = eg*2 + m;
      const float as = a_s_sh[e];
      #pragma unroll
      for (int j = 0; j < 4; j++){
        const int o = og*4 + j;
        s_buf[e][o] = (as*acc_a[j][m] + acc_b[j][m]) * INV_U0 + b0[o];
      }
    }
  }
  float accT[4] = {0.f,0.f,0.f,0.f};
  gemm_t_n<128, 0>(accT, Wsv0, A_T, t);
  float accU[3][4] = {};
  gemm_u_n<128>(accU, Wvv0, V_T, t);
  __syncthreads();
  {
    const int og = t & 15, e = t >> 4;
    const float as = a_s_sh[e];
    const float a0 = av_sh[e][0], a1 = av_sh[e][1], a2 = av_sh[e][2];
    #pragma unroll
    for (int j = 0; j < 4; j++){
      const int o = og*4 + j;
      const float s1v = s_buf[e][o];
      const float hs = s1v * fast_sigmoid(s1v);
      const float g  = fast_sigmoid(s_buf[e][64+o]);
      const float tt = accT[j];
      const float hv0 = (tt*a0 + as*accU[0][j]) * INV_U0 * g;
      const float hv1 = (tt*a1 + as*accU[1][j]) * INV_U0 * g;
      const float hv2 = (tt*a2 + as*accU[2][j]) * INV_U0 * g;
      A_T[o][e] = hs;
      V_T[o][e] = hv0; V_T[o][16+e] = hv1; V_T[o][32+e] = hv2;
      A_T[64+o][e] = (hv0*a0 + hv1*a1 + hv2*a2) * RSQRT3;
    }
  }
  __syncthreads();

  float sa[4] = {0.f,0.f,0.f,0.f};
  float sb[4] = {0.f,0.f,0.f,0.f};
  gemm_t_n<64, 0>(sa, Wss1, A_T, t);
  gemm_t_n<64, 64>(sb, Wvs1, A_T, t);
  float accT2[4] = {0.f,0.f,0.f,0.f};
  gemm_t_n<64, 0>(accT2, Wsv1, A_T, t);
  float accU2[3][4] = {};
  gemm_u_n<64>(accU2, Wvv1, V_T, t);
  {
    const int og = t & 15, e = t >> 4;
    const int n = n0 + e;
    const float as = a_s_sh[e];
    const float a0 = av_sh[e][0], a1 = av_sh[e][1], a2 = av_sh[e][2];
    #pragma unroll
    for (int j = 0; j < 4; j++){
      const int o = og*4 + j;
      const float us = (as*sa[j] + sb[j]) * INV_U1 + b1u[o];
      out[(size_t)n*256 + o] = node_s[(size_t)n*64 + o] + us;
      const float tt = accT2[j];
      out[(size_t)n*256 + 64 + o*3 + 0] = node_v[(size_t)n*192 + o*3 + 0] + (tt*a0 + as*accU2[0][j]) * INV_U1;
      out[(size_t)n*256 + 64 + o*3 + 1] = node_v[(size_t)n*192 + o*3 + 1] + (tt*a1 + as*accU2[1][j]) * INV_U1;
      out[(size_t)n*256 + 64 + o*3 + 2] = node_v[(size_t)n*192 + o*3 + 2] + (tt*a2 + as*accU2[2][j]) * INV_U1;
    }
  }
}

extern "C" void kernel_launch(void* const* d_in, const int* in_sizes, int n_in,
                              void* d_out, int out_size, void* d_ws, size_t ws_size,
                              hipStream_t stream) {
  const float* node_s      = (const float*)d_in[0];
  const float* node_v      = (const float*)d_in[1];
  const float* node_attr_s = (const float*)d_in[2];
  const float* node_attr_v = (const float*)d_in[3];
  const float* edge_attr_s = (const float*)d_in[4];
  const float* edge_attr_v = (const float*)d_in[5];
  const float* add_feat    = (const float*)d_in[6];
  const float* m1_Wss = (const float*)d_in[7];
  const float* m1_Wvs = (const float*)d_in[8];
  const float* m1_Wsv = (const float*)d_in[9];
  const float* m1_Wvv = (const float*)d_in[10];
  const float* m1_b   = (const float*)d_in[11];
  const float* m2_Wss = (const float*)d_in[12];
  const float* m2_Wvs = (const float*)d_in[13];
  const float* m2_Wsv = (const float*)d_in[14];
  const float* m2_Wvv = (const float*)d_in[15];
  const float* m2_b   = (const float*)d_in[16];
  const float* u0_Wss = (const float*)d_in[17];
  const float* u0_Wvs = (const float*)d_in[18];
  const float* u0_Wsv = (const float*)d_in[19];
  const float* u0_Wvv = (const float*)d_in[20];
  const float* u0_b   = (const float*)d_in[21];
  const float* u1_Wss = (const float*)d_in[22];
  const float* u1_Wvs = (const float*)d_in[23];
  const float* u1_Wsv = (const float*)d_in[24];
  const float* u1_Wvv = (const float*)d_in[25];
  const float* u1_b   = (const float*)d_in[26];
  const int* senders   = (const int*)d_in[27];
  const int* receivers = (const int*)d_in[28];
  float* out = (float*)d_out;

  // small workspace: CSR only (~2 MB)
  const size_t ELIST_BYTES = (size_t)NEDGES * sizeof(int);
  const size_t OFFS_BYTES  = (size_t)(NNODES + 1) * sizeof(int);
  const size_t CUR_BYTES   = (size_t)NNODES * sizeof(int);
  const size_t NEED = ELIST_BYTES + OFFS_BYTES + CUR_BYTES;

  hipMemsetAsync(d_out, 0, (size_t)out_size * sizeof(float), stream);

  if (ws_size >= NEED){
    char* w = (char*)d_ws;
    int* elist = (int*)w;
    int* offs  = (int*)(w + ELIST_BYTES);
    int* cnt   = (int*)(w + ELIST_BYTES + OFFS_BYTES);

    hipMemsetAsync(cnt, 0, CUR_BYTES, stream);
    hist_kernel<<<(NEDGES + 255) / 256, 256, 0, stream>>>(receivers, cnt);
    scan_kernel<<<1, 1024, 0, stream>>>(cnt, offs);
    hipMemsetAsync(cnt, 0, CUR_BYTES, stream);
    place_kernel<<<(NEDGES + 255) / 256, 256, 0, stream>>>(receivers, offs, cnt, elist);

    edge_kernel<1><<<NEDGES / ET, 512, 0, stream>>>(
        node_s, node_v, edge_attr_s, edge_attr_v, add_feat, senders, receivers, elist,
        m1_Wss, m1_Wvs, m1_Wsv, m1_Wvv, m1_b,
        m2_Wss, m2_Wvs, m2_Wsv, m2_Wvv, m2_b, out);
  } else {
    edge_kernel<0><<<NEDGES / ET, 512, 0, stream>>>(
        node_s, node_v, edge_attr_s, edge_attr_v, add_feat, senders, receivers, nullptr,
        m1_Wss, m1_Wvs, m1_Wsv, m1_Wvv, m1_b,
        m2_Wss, m2_Wvs, m2_Wsv, m2_Wvv, m2_b, out);
  }

  node_kernel<<<NNODES / TE, 256, 0, stream>>>(
      node_s, node_v, node_attr_s, node_attr_v,
      u0_Wss, u0_Wvs, u0_Wsv, u0_Wvv, u0_b,
      u1_Wss, u1_Wvs, u1_Wsv, u1_Wvv, u1_b, out);
}